// Round 1
// baseline (317.127 us; speedup 1.0000x reference)
//
#include <hip/hip_runtime.h>

// FourierLayer: rfft2 -> keep 64x64 modes -> per-mode channel mix -> irfft2
// + channelwise skip + gelu.  All DFTs collapse to dense GEMMs (only 64x64
// modes survive).  External dtype (fp32 vs bf16) is UNKNOWN -> detected at
// runtime by `sniff` (low-u16 of fp32 words = random mantissa bits; low-u16
// of bf16 pairs = a bf16 whose exponent lands in [110,130] for N(0,1) data).
// Internal intermediates are always bf16 (threshold is 2% relative).
//
// Memory plan:
//   ws:    EW/Gi/Ct/wt/bias/flag tables (0.41 MB) + yt (2 MB)
//   d_out: phase1 t1T [0,8MB) -> phase2 P [8,10MB) -> conv (full, out dtype)
// Stages:
//   A: t1T[i](128x512) = EW(128x512) @ x[i](512x512)^T      (W-axis DFT)
//   B: P[i](128x128)   = EW(128x512) @ t1T[i]^T             (H-axis DFT)
//   C: yt[o](128x128)  = mode mix, sym 2x2 blocks [[yR,yI],[yI,-yR]] -> ws
//   D+E fused: conv[o] = (Gi @ yt[o]^T) @ Ct^T -> d_out
//   F: out = gelu(conv + b_conv + w_skip@x + b_skip)   (in-place on d_out)

using bf16x8 = __attribute__((ext_vector_type(8))) short;
using f32x4  = __attribute__((ext_vector_type(4))) float;
typedef unsigned short u16;

__device__ __forceinline__ u16 f2bf(float f) {
  unsigned u = __float_as_uint(f);
  u = u + 0x7FFFu + ((u >> 16) & 1u);   // round-to-nearest-even
  return (u16)(u >> 16);
}
__device__ __forceinline__ float bf2f(u16 v) {
  return __uint_as_float(((unsigned)v) << 16);
}
// flag==1 -> externals are fp32; flag==0 -> externals are bf16
__device__ __forceinline__ float rdx(const void* p, size_t i, int f32) {
  return f32 ? ((const float*)p)[i] : bf2f(((const u16*)p)[i]);
}

// ---------------- dtype sniff ----------------------------------------------
__global__ void sniff(const unsigned* __restrict__ xw, int* __restrict__ flag) {
  unsigned u = xw[threadIdx.x];
  int e = (u >> 7) & 0xFF;                  // bf16-pair: exponent of low bf16
  unsigned long long m = __ballot(e >= 110 && e <= 130);
  if (threadIdx.x == 0) *flag = (__popcll(m) < 32) ? 1 : 0;   // 1 = fp32
}

// ---------------- twiddle tables + wskip transpose + fused bias ------------
__global__ __launch_bounds__(256) void init_tables(
    const void* __restrict__ wskip, const void* __restrict__ bconv,
    const void* __restrict__ bskip, const int* __restrict__ flag,
    u16* __restrict__ EW,    // [128][512]  fwd DFT (stages A and B)
    u16* __restrict__ Gi,    // [512][128]  inv DFT rows=h, cols=2kx|2kx+1
    u16* __restrict__ Ct,    // [512][128]  irfft rows=w
    float* __restrict__ wt,  // [i][o] transposed skip weights (fp32)
    float* __restrict__ bias) {
  const int f32 = *flag;
  int t = blockIdx.x * blockDim.x + threadIdx.x;   // 0..65535
  {
    // EW[m][n]: f=m>>1, part=m&1 -> part? -sin : cos of 2*pi*f*n/512
    int m = t >> 9, n = t & 511;
    int f = m >> 1, part = m & 1;
    int idx = (f * n) & 511;
    float ang = 0.01227184630308513f * (float)idx;  // 2*pi/512
    float s, c; __sincosf(ang, &s, &c);
    EW[t] = f2bf(part ? -s : c);
  }
  {
    int h = t >> 7, cc = t & 127;
    int f = cc >> 1, part = cc & 1;
    int idx = (f * h) & 511;
    float ang = 0.01227184630308513f * (float)idx;
    float s, c; __sincosf(ang, &s, &c);
    // inverse along H: e^{+i}/512 -> (cos, -sin) against [[yR,yI],[yI,-yR]]
    Gi[t] = f2bf((part ? -s : c) * (1.0f / 512.0f));
    // irfft along W: (1 if ky==0 else 2)/512 * (cos | -sin); sin(0)=0 drops Im(bin0)
    float scale = (f == 0 ? 1.0f : 2.0f) * (1.0f / 512.0f);
    Ct[t] = f2bf((part ? -s : c) * scale);
  }
  if (t < 4096) {
    int o = t >> 6, i = t & 63;
    wt[i * 64 + o] = rdx(wskip, o * 64 + i, f32);
  }
  if (t < 64) bias[t] = rdx(bconv, t, f32) + rdx(bskip, t, f32);
}

// ---------------- stage A GEMM: B operand is the external x ----------------
// C[m][n] = sum_k A[m][k] * Bt[n][k];  blockIdx.z = batch (channel i).
// LDS row stride 72 elems = 144 B = 9*16 B (every b128 16B-aligned).
__global__ __launch_bounds__(256) void gemm_bt_x(
    const u16* __restrict__ A,  int lda,
    const void* __restrict__ BtV, int ldb, long long sB,
    u16* __restrict__ C,        int ldc, long long sC,
    int K, const int* __restrict__ flag) {
  const int f32 = *flag;
  const float* BtF = (const float*)BtV + (long long)blockIdx.z * sB;
  const u16*   BtH = (const u16*)BtV + (long long)blockIdx.z * sB;
  const int m0 = blockIdx.y * 64, n0 = blockIdx.x * 64;
  __shared__ __align__(16) u16 As[64][72];
  __shared__ __align__(16) u16 Bs[64][72];
  const int tid  = threadIdx.x;
  const int lane = tid & 63, wave = tid >> 6;
  const int srow = tid >> 2, sseg = (tid & 3) * 8;
  const int mb = (wave & 1) * 32, nb = (wave >> 1) * 32;
  const int fr = lane & 15, koff = (lane >> 4) * 8;
  f32x4 z = {0.f, 0.f, 0.f, 0.f};
  f32x4 acc00 = z, acc01 = z, acc10 = z, acc11 = z;
  for (int k0 = 0; k0 < K; k0 += 32) {
    __syncthreads();
    *(uint4*)&As[srow][sseg] = *(const uint4*)&A[(size_t)(m0 + srow) * lda + k0 + sseg];
    size_t bofs = (size_t)(n0 + srow) * ldb + k0 + sseg;
    if (f32) {
      float4 u = *(const float4*)(BtF + bofs);
      float4 v = *(const float4*)(BtF + bofs + 4);
      uint4 w;
      w.x = (unsigned)f2bf(u.x) | ((unsigned)f2bf(u.y) << 16);
      w.y = (unsigned)f2bf(u.z) | ((unsigned)f2bf(u.w) << 16);
      w.z = (unsigned)f2bf(v.x) | ((unsigned)f2bf(v.y) << 16);
      w.w = (unsigned)f2bf(v.z) | ((unsigned)f2bf(v.w) << 16);
      *(uint4*)&Bs[srow][sseg] = w;
    } else {
      *(uint4*)&Bs[srow][sseg] = *(const uint4*)(BtH + bofs);
    }
    __syncthreads();
    bf16x8 a0 = *(const bf16x8*)&As[mb + fr][koff];
    bf16x8 a1 = *(const bf16x8*)&As[mb + 16 + fr][koff];
    bf16x8 b0 = *(const bf16x8*)&Bs[nb + fr][koff];
    bf16x8 b1 = *(const bf16x8*)&Bs[nb + 16 + fr][koff];
    acc00 = __builtin_amdgcn_mfma_f32_16x16x32_bf16(a0, b0, acc00, 0, 0, 0);
    acc01 = __builtin_amdgcn_mfma_f32_16x16x32_bf16(a0, b1, acc01, 0, 0, 0);
    acc10 = __builtin_amdgcn_mfma_f32_16x16x32_bf16(a1, b0, acc10, 0, 0, 0);
    acc11 = __builtin_amdgcn_mfma_f32_16x16x32_bf16(a1, b1, acc11, 0, 0, 0);
  }
  // C/D layout: col = lane&15, row = (lane>>4)*4 + reg
  const int col = lane & 15, rb = (lane >> 4) * 4;
  f32x4 accs[2][2] = {{acc00, acc01}, {acc10, acc11}};
  for (int mt = 0; mt < 2; ++mt)
    for (int nt = 0; nt < 2; ++nt)
      for (int r = 0; r < 4; ++r) {
        int mrow = m0 + mb + mt * 16 + rb + r;
        int ncol = n0 + nb + nt * 16 + col;
        C[(size_t)mrow * ldc + ncol] = f2bf(accs[mt][nt][r]);
      }
}

// ---------------- stage B GEMM: all-bf16 internal --------------------------
__global__ __launch_bounds__(256) void gemm_bt(
    const u16* __restrict__ A,  int lda, long long sA,
    const u16* __restrict__ Bt, int ldb, long long sB,
    u16* __restrict__ C,        int ldc, long long sC,
    int K) {
  A  += (long long)blockIdx.z * sA;
  Bt += (long long)blockIdx.z * sB;
  C  += (long long)blockIdx.z * sC;
  const int m0 = blockIdx.y * 64, n0 = blockIdx.x * 64;
  __shared__ __align__(16) u16 As[64][72];
  __shared__ __align__(16) u16 Bs[64][72];
  const int tid  = threadIdx.x;
  const int lane = tid & 63, wave = tid >> 6;
  const int srow = tid >> 2, sseg = (tid & 3) * 8;
  const int mb = (wave & 1) * 32, nb = (wave >> 1) * 32;
  const int fr = lane & 15, koff = (lane >> 4) * 8;
  f32x4 z = {0.f, 0.f, 0.f, 0.f};
  f32x4 acc00 = z, acc01 = z, acc10 = z, acc11 = z;
  for (int k0 = 0; k0 < K; k0 += 32) {
    __syncthreads();
    *(uint4*)&As[srow][sseg] = *(const uint4*)&A[(size_t)(m0 + srow) * lda + k0 + sseg];
    *(uint4*)&Bs[srow][sseg] = *(const uint4*)&Bt[(size_t)(n0 + srow) * ldb + k0 + sseg];
    __syncthreads();
    bf16x8 a0 = *(const bf16x8*)&As[mb + fr][koff];
    bf16x8 a1 = *(const bf16x8*)&As[mb + 16 + fr][koff];
    bf16x8 b0 = *(const bf16x8*)&Bs[nb + fr][koff];
    bf16x8 b1 = *(const bf16x8*)&Bs[nb + 16 + fr][koff];
    acc00 = __builtin_amdgcn_mfma_f32_16x16x32_bf16(a0, b0, acc00, 0, 0, 0);
    acc01 = __builtin_amdgcn_mfma_f32_16x16x32_bf16(a0, b1, acc01, 0, 0, 0);
    acc10 = __builtin_amdgcn_mfma_f32_16x16x32_bf16(a1, b0, acc10, 0, 0, 0);
    acc11 = __builtin_amdgcn_mfma_f32_16x16x32_bf16(a1, b1, acc11, 0, 0, 0);
  }
  const int col = lane & 15, rb = (lane >> 4) * 4;
  f32x4 accs[2][2] = {{acc00, acc01}, {acc10, acc11}};
  for (int mt = 0; mt < 2; ++mt)
    for (int nt = 0; nt < 2; ++nt)
      for (int r = 0; r < 4; ++r) {
        int mrow = m0 + mb + mt * 16 + rb + r;
        int ncol = n0 + nb + nt * 16 + col;
        C[(size_t)mrow * ldc + ncol] = f2bf(accs[mt][nt][r]);
      }
}

// ---------------- stage C: per-mode 64ch complex contraction ----------------
__global__ __launch_bounds__(256) void modemix(
    const u16* __restrict__ P, const void* __restrict__ wre,
    const void* __restrict__ wim, u16* __restrict__ yt,
    const int* __restrict__ flag) {
  const int f32 = *flag;
  const int o = blockIdx.x >> 4;
  const int kxg = blockIdx.x & 15;
  const int tid = threadIdx.x;
  const int ky = tid & 63;
  const int kxj = tid >> 6;               // 0..3
  const int kx = kxg * 4 + kxj;
  float yR = 0.f, yI = 0.f;
  for (int i = 0; i < 64; ++i) {
    const u16* prow = P + i * 16384 + (2 * kx) * 128 + 2 * ky;
    unsigned p0 = *(const unsigned*)prow;          // [2kx][2ky], [2kx][2ky+1]
    unsigned p1 = *(const unsigned*)(prow + 128);  // [2kx+1][...]
    float p00 = bf2f((u16)(p0 & 0xFFFF)), p01 = bf2f((u16)(p0 >> 16));
    float p10 = bf2f((u16)(p1 & 0xFFFF)), p11 = bf2f((u16)(p1 >> 16));
    float xr = p00 - p11;
    float xi = p01 + p10;
    size_t widx = ((size_t)(i * 64 + o) * 64 + kx) * 64 + ky;
    float wr = rdx(wre, widx, f32);
    float wq = rdx(wim, widx, f32);
    yR += xr * wr - xi * wq;
    yI += xr * wq + xi * wr;
  }
  __shared__ u16 T[128][12];   // 24 B rows keep ushort4 (8 B) reads aligned
  T[2 * ky][2 * kxj]         = f2bf(yR);
  T[2 * ky][2 * kxj + 1]     = f2bf(yI);
  T[2 * ky + 1][2 * kxj]     = f2bf(yI);
  T[2 * ky + 1][2 * kxj + 1] = f2bf(-yR);
  __syncthreads();
  int r = tid >> 1, s = (tid & 1) * 4;
  u16* dst = yt + (size_t)o * 16384 + (size_t)r * 128 + kxg * 8 + s;
  ushort4 v;
  v.x = T[r][s]; v.y = T[r][s + 1]; v.z = T[r][s + 2]; v.w = T[r][s + 3];
  *(ushort4*)dst = v;
}

// ---------------- fused D+E: conv[o] stripe = (Gi @ yt[o]^T) @ Ct^T --------
// LDS stride 136 elems = 272 B = 17*16 (aligned b128).
__global__ __launch_bounds__(256) void inv_conv(
    const u16* __restrict__ Gi, const u16* __restrict__ Ct,
    const u16* __restrict__ yt, void* __restrict__ convV,
    const int* __restrict__ flag) {
  const int f32 = *flag;
  float* convF = (float*)convV;
  u16*   convH = (u16*)convV;
  const int m0 = blockIdx.x * 64;
  const int o  = blockIdx.y;
  __shared__ __align__(16) u16 lds[26112];   // 52 KB
  u16* As = lds;          // [64][136]  Gi tile;  later Cs (Ct tile)
  u16* Bs = lds + 8704;   // [128][136] yt;       later T [64][136]
  const int tid = threadIdx.x, lane = tid & 63, wave = tid >> 6;
  const int fr = lane & 15, koff = (lane >> 4) * 8;
  const int col = lane & 15, rb = (lane >> 4) * 4;
  {  // stage Gi tile (64x128)
    int r = tid >> 2, cs = (tid & 3) * 32;
    const u16* g = Gi + (size_t)(m0 + r) * 128 + cs;
    u16* d = As + r * 136 + cs;
#pragma unroll
    for (int j = 0; j < 4; ++j) *(uint4*)(d + 8 * j) = *(const uint4*)(g + 8 * j);
  }
  {  // stage full yt[o] (128x128)
    int r = tid >> 1, cs = (tid & 1) * 64;
    const u16* g = yt + (size_t)o * 16384 + (size_t)r * 128 + cs;
    u16* d = Bs + r * 136 + cs;
#pragma unroll
    for (int j = 0; j < 8; ++j) *(uint4*)(d + 8 * j) = *(const uint4*)(g + 8 * j);
  }
  __syncthreads();
  const int mb = (wave & 1) * 32, nh = (wave >> 1) * 64;
  f32x4 z = {0.f, 0.f, 0.f, 0.f};
  f32x4 acc1[2][4];
#pragma unroll
  for (int mt = 0; mt < 2; ++mt)
#pragma unroll
    for (int nt = 0; nt < 4; ++nt) acc1[mt][nt] = z;
  for (int k0 = 0; k0 < 128; k0 += 32) {
    bf16x8 a0 = *(const bf16x8*)(As + (mb + fr) * 136 + k0 + koff);
    bf16x8 a1 = *(const bf16x8*)(As + (mb + 16 + fr) * 136 + k0 + koff);
#pragma unroll
    for (int nt = 0; nt < 4; ++nt) {
      bf16x8 b = *(const bf16x8*)(Bs + (nh + nt * 16 + fr) * 136 + k0 + koff);
      acc1[0][nt] = __builtin_amdgcn_mfma_f32_16x16x32_bf16(a0, b, acc1[0][nt], 0, 0, 0);
      acc1[1][nt] = __builtin_amdgcn_mfma_f32_16x16x32_bf16(a1, b, acc1[1][nt], 0, 0, 0);
    }
  }
  __syncthreads();   // all As/Bs reads done before T overwrites Bs
  u16* T = Bs;       // [64][136], rows = m, cols = c
#pragma unroll
  for (int mt = 0; mt < 2; ++mt)
#pragma unroll
    for (int nt = 0; nt < 4; ++nt)
#pragma unroll
      for (int r = 0; r < 4; ++r)
        T[(mb + mt * 16 + rb + r) * 136 + nh + nt * 16 + col] = f2bf(acc1[mt][nt][r]);
  u16* Cs = lds;     // alias As
  const int mb2 = (wave & 1) * 32, nb2 = (wave >> 1) * 32;
  for (int nb0 = 0; nb0 < 8; ++nb0) {
    __syncthreads();
    {
      int r = tid >> 2, cs = (tid & 3) * 32;
      const u16* g = Ct + (size_t)(nb0 * 64 + r) * 128 + cs;
      u16* d = Cs + r * 136 + cs;
#pragma unroll
      for (int j = 0; j < 4; ++j) *(uint4*)(d + 8 * j) = *(const uint4*)(g + 8 * j);
    }
    __syncthreads();
    f32x4 acc2[2][2] = {{z, z}, {z, z}};
    for (int k0 = 0; k0 < 128; k0 += 32) {
      bf16x8 a0 = *(const bf16x8*)(T + (mb2 + fr) * 136 + k0 + koff);
      bf16x8 a1 = *(const bf16x8*)(T + (mb2 + 16 + fr) * 136 + k0 + koff);
      bf16x8 b0 = *(const bf16x8*)(Cs + (nb2 + fr) * 136 + k0 + koff);
      bf16x8 b1 = *(const bf16x8*)(Cs + (nb2 + 16 + fr) * 136 + k0 + koff);
      acc2[0][0] = __builtin_amdgcn_mfma_f32_16x16x32_bf16(a0, b0, acc2[0][0], 0, 0, 0);
      acc2[0][1] = __builtin_amdgcn_mfma_f32_16x16x32_bf16(a0, b1, acc2[0][1], 0, 0, 0);
      acc2[1][0] = __builtin_amdgcn_mfma_f32_16x16x32_bf16(a1, b0, acc2[1][0], 0, 0, 0);
      acc2[1][1] = __builtin_amdgcn_mfma_f32_16x16x32_bf16(a1, b1, acc2[1][1], 0, 0, 0);
    }
#pragma unroll
    for (int mt = 0; mt < 2; ++mt)
#pragma unroll
      for (int nt = 0; nt < 2; ++nt)
#pragma unroll
        for (int r = 0; r < 4; ++r) {
          size_t idx = (size_t)o * 262144 + (size_t)(m0 + mb2 + mt * 16 + rb + r) * 512
                     + nb0 * 64 + nb2 + nt * 16 + col;
          float v = acc2[mt][nt][r];
          if (f32) convF[idx] = v; else convH[idx] = f2bf(v);
        }
  }
}

// ---------------- skip GEMM + bias + gelu + store --------------------------
__global__ __launch_bounds__(256) void skip_final(
    const void* __restrict__ x, const float* __restrict__ wt,
    const float* __restrict__ bias, void* __restrict__ outV,
    const int* __restrict__ flag) {
  const int f32 = *flag;
  float* outF = (float*)outV;
  u16*   outH = (u16*)outV;
  const size_t p = (size_t)blockIdx.x * 256 + threadIdx.x;  // pixel (h,w)
  float acc[64];
#pragma unroll
  for (int o = 0; o < 64; ++o) acc[o] = 0.f;
  for (int i = 0; i < 64; ++i) {
    float xv = rdx(x, (size_t)i * 262144 + p, f32);
    const float* wr = wt + i * 64;        // wave-uniform -> s_loads
#pragma unroll
    for (int o = 0; o < 64; ++o) acc[o] = fmaf(xv, wr[o], acc[o]);
  }
#pragma unroll
  for (int o = 0; o < 64; ++o) {
    size_t idx = (size_t)o * 262144 + p;
    float cv = f32 ? outF[idx] : bf2f(outH[idx]);
    float v = acc[o] + cv + bias[o];
    // gelu(tanh approx) = v * sigmoid(2*0.7978845608*(v + 0.044715 v^3))
    float zz = 1.5957691216f * (v + 0.044715f * v * v * v);
    float g = v / (1.f + __expf(-zz));
    if (f32) outF[idx] = g; else outH[idx] = f2bf(g);
  }
}

extern "C" void kernel_launch(void* const* d_in, const int* in_sizes, int n_in,
                              void* d_out, int out_size, void* d_ws, size_t ws_size,
                              hipStream_t stream) {
  const void* x     = d_in[0];   // (64,512,512)
  const void* wre   = d_in[1];   // (64,64,64,64)
  const void* wim   = d_in[2];
  const void* bconv = d_in[3];   // (64,)
  const void* wskip = d_in[4];   // (64,64)
  const void* bskip = d_in[5];   // (64,)
  char* ws = (char*)d_ws;

  // ws layout (total 2.5 MB)
  u16*   EW   = (u16*)(ws);                            // 128 KB
  u16*   Gi   = (u16*)(ws + (1 << 17));                // 128 KB
  u16*   Ct   = (u16*)(ws + (2 << 17));                // 128 KB
  float* wt   = (float*)(ws + 3 * (1 << 17));          // 16 KB
  float* bias = (float*)(ws + 3 * (1 << 17) + 16384);  // 256 B
  int*   flag = (int*)(ws + 3 * (1 << 17) + 16640);    // 4 B
  u16*   yt   = (u16*)(ws + (1 << 19));                // 2 MB
  // d_out doubles as scratch before stage D+E (byte offsets; fits either dtype):
  u16* t1T = (u16*)d_out;                    // [0, 8MB):  64 x (128x512) bf16
  u16* P   = (u16*)((char*)d_out + (8 << 20));  // [8,10MB): 64 x (128x128) bf16

  sniff<<<1, 64, 0, stream>>>((const unsigned*)x, flag);
  init_tables<<<256, 256, 0, stream>>>(wskip, bconv, bskip, flag, EW, Gi, Ct, wt, bias);
  // A: t1T[i](128x512) = EW @ x[i]^T        M=128 N=512 K=512, batch 64
  gemm_bt_x<<<dim3(8, 2, 64), 256, 0, stream>>>(EW, 512, x, 512, 262144, t1T, 512, 65536, 512, flag);
  // B: P[i](128x128) = EW @ t1T[i]^T        M=128 N=128 K=512
  gemm_bt<<<dim3(2, 2, 64), 256, 0, stream>>>(EW, 512, 0, t1T, 512, 65536, P, 128, 16384, 512);
  // C: mode mix -> yt[o] in ws (sym 2x2 layout)
  modemix<<<1024, 256, 0, stream>>>(P, wre, wim, yt, flag);
  // D+E fused: conv -> d_out (overwrites t1T/P scratch, both dead)
  inv_conv<<<dim3(8, 64), 256, 0, stream>>>(Gi, Ct, yt, d_out, flag);
  // F: skip + bias + gelu (in-place on d_out)
  skip_final<<<1024, 256, 0, stream>>>(x, wt, bias, d_out, flag);
}

// Round 2
// 309.436 us; speedup vs baseline: 1.0249x; 1.0249x over previous
//
#include <hip/hip_runtime.h>

// FourierLayer: rfft2 -> keep 64x64 modes -> per-mode channel mix -> irfft2
// + channelwise skip + gelu.  All DFTs collapse to dense GEMMs (only 64x64
// modes survive).  External dtype (fp32 vs bf16) is UNKNOWN -> detected at
// runtime by `sniff`.  Internal intermediates are always bf16.
//
// Memory plan:
//   ws:    EW/Gi/Ct/wbf/bias/flag tables (0.41 MB) + yt (2 MB)
//   d_out: phase1 t1T [0,8MB) -> phase2 P [8,10MB) -> conv (full, out dtype)
// Stages:
//   A: t1T[i](128x512) = EW(128x512) @ x[i](512x512)^T      (W-axis DFT)
//   B: P[i](128x128)   = EW(128x512) @ t1T[i]^T             (H-axis DFT)
//   C: yt[o](128x128)  = mode mix, sym 2x2 blocks [[yR,yI],[yI,-yR]] -> ws
//   D+E fused: conv[o] = (Gi @ yt[o]^T) @ Ct^T -> d_out
//   F: out = gelu(conv + bias + w_skip@x)  -- MFMA skip GEMM, in-place d_out
//      (R1 change: skip GEMM moved from 64 scalar-FMA/pixel VALU loop to
//       mfma_f32_16x16x32_bf16; x tile transposed through LDS.)

using bf16x8 = __attribute__((ext_vector_type(8))) short;
using f32x4  = __attribute__((ext_vector_type(4))) float;
typedef unsigned short u16;

__device__ __forceinline__ u16 f2bf(float f) {
  unsigned u = __float_as_uint(f);
  u = u + 0x7FFFu + ((u >> 16) & 1u);   // round-to-nearest-even
  return (u16)(u >> 16);
}
__device__ __forceinline__ float bf2f(u16 v) {
  return __uint_as_float(((unsigned)v) << 16);
}
// flag==1 -> externals are fp32; flag==0 -> externals are bf16
__device__ __forceinline__ float rdx(const void* p, size_t i, int f32) {
  return f32 ? ((const float*)p)[i] : bf2f(((const u16*)p)[i]);
}

// ---------------- dtype sniff ----------------------------------------------
__global__ void sniff(const unsigned* __restrict__ xw, int* __restrict__ flag) {
  unsigned u = xw[threadIdx.x];
  int e = (u >> 7) & 0xFF;                  // bf16-pair: exponent of low bf16
  unsigned long long m = __ballot(e >= 110 && e <= 130);
  if (threadIdx.x == 0) *flag = (__popcll(m) < 32) ? 1 : 0;   // 1 = fp32
}

// ---------------- twiddle tables + wskip bf16 + fused bias ------------------
__global__ __launch_bounds__(256) void init_tables(
    const void* __restrict__ wskip, const void* __restrict__ bconv,
    const void* __restrict__ bskip, const int* __restrict__ flag,
    u16* __restrict__ EW,    // [128][512]  fwd DFT (stages A and B)
    u16* __restrict__ Gi,    // [512][128]  inv DFT rows=h, cols=2kx|2kx+1
    u16* __restrict__ Ct,    // [512][128]  irfft rows=w
    u16* __restrict__ wbf,   // [o][i] skip weights, bf16 (MFMA A operand)
    float* __restrict__ bias) {
  const int f32 = *flag;
  int t = blockIdx.x * blockDim.x + threadIdx.x;   // 0..65535
  {
    // EW[m][n]: f=m>>1, part=m&1 -> part? -sin : cos of 2*pi*f*n/512
    int m = t >> 9, n = t & 511;
    int f = m >> 1, part = m & 1;
    int idx = (f * n) & 511;
    float ang = 0.01227184630308513f * (float)idx;  // 2*pi/512
    float s, c; __sincosf(ang, &s, &c);
    EW[t] = f2bf(part ? -s : c);
  }
  {
    int h = t >> 7, cc = t & 127;
    int f = cc >> 1, part = cc & 1;
    int idx = (f * h) & 511;
    float ang = 0.01227184630308513f * (float)idx;
    float s, c; __sincosf(ang, &s, &c);
    // inverse along H: e^{+i}/512 -> (cos, -sin) against [[yR,yI],[yI,-yR]]
    Gi[t] = f2bf((part ? -s : c) * (1.0f / 512.0f));
    // irfft along W: (1 if ky==0 else 2)/512 * (cos | -sin)
    float scale = (f == 0 ? 1.0f : 2.0f) * (1.0f / 512.0f);
    Ct[t] = f2bf((part ? -s : c) * scale);
  }
  if (t < 4096) wbf[t] = f2bf(rdx(wskip, t, f32));   // [o][i] row-major
  if (t < 64) bias[t] = rdx(bconv, t, f32) + rdx(bskip, t, f32);
}

// ---------------- stage A GEMM: B operand is the external x ----------------
// C[m][n] = sum_k A[m][k] * Bt[n][k];  blockIdx.z = batch (channel i).
// LDS row stride 72 elems = 144 B = 9*16 B (every b128 16B-aligned).
__global__ __launch_bounds__(256) void gemm_bt_x(
    const u16* __restrict__ A,  int lda,
    const void* __restrict__ BtV, int ldb, long long sB,
    u16* __restrict__ C,        int ldc, long long sC,
    int K, const int* __restrict__ flag) {
  const int f32 = *flag;
  const float* BtF = (const float*)BtV + (long long)blockIdx.z * sB;
  const u16*   BtH = (const u16*)BtV + (long long)blockIdx.z * sB;
  const int m0 = blockIdx.y * 64, n0 = blockIdx.x * 64;
  __shared__ __align__(16) u16 As[64][72];
  __shared__ __align__(16) u16 Bs[64][72];
  const int tid  = threadIdx.x;
  const int lane = tid & 63, wave = tid >> 6;
  const int srow = tid >> 2, sseg = (tid & 3) * 8;
  const int mb = (wave & 1) * 32, nb = (wave >> 1) * 32;
  const int fr = lane & 15, koff = (lane >> 4) * 8;
  f32x4 z = {0.f, 0.f, 0.f, 0.f};
  f32x4 acc00 = z, acc01 = z, acc10 = z, acc11 = z;
  for (int k0 = 0; k0 < K; k0 += 32) {
    __syncthreads();
    *(uint4*)&As[srow][sseg] = *(const uint4*)&A[(size_t)(m0 + srow) * lda + k0 + sseg];
    size_t bofs = (size_t)(n0 + srow) * ldb + k0 + sseg;
    if (f32) {
      float4 u = *(const float4*)(BtF + bofs);
      float4 v = *(const float4*)(BtF + bofs + 4);
      uint4 w;
      w.x = (unsigned)f2bf(u.x) | ((unsigned)f2bf(u.y) << 16);
      w.y = (unsigned)f2bf(u.z) | ((unsigned)f2bf(u.w) << 16);
      w.z = (unsigned)f2bf(v.x) | ((unsigned)f2bf(v.y) << 16);
      w.w = (unsigned)f2bf(v.z) | ((unsigned)f2bf(v.w) << 16);
      *(uint4*)&Bs[srow][sseg] = w;
    } else {
      *(uint4*)&Bs[srow][sseg] = *(const uint4*)(BtH + bofs);
    }
    __syncthreads();
    bf16x8 a0 = *(const bf16x8*)&As[mb + fr][koff];
    bf16x8 a1 = *(const bf16x8*)&As[mb + 16 + fr][koff];
    bf16x8 b0 = *(const bf16x8*)&Bs[nb + fr][koff];
    bf16x8 b1 = *(const bf16x8*)&Bs[nb + 16 + fr][koff];
    acc00 = __builtin_amdgcn_mfma_f32_16x16x32_bf16(a0, b0, acc00, 0, 0, 0);
    acc01 = __builtin_amdgcn_mfma_f32_16x16x32_bf16(a0, b1, acc01, 0, 0, 0);
    acc10 = __builtin_amdgcn_mfma_f32_16x16x32_bf16(a1, b0, acc10, 0, 0, 0);
    acc11 = __builtin_amdgcn_mfma_f32_16x16x32_bf16(a1, b1, acc11, 0, 0, 0);
  }
  // C/D layout: col = lane&15, row = (lane>>4)*4 + reg
  const int col = lane & 15, rb = (lane >> 4) * 4;
  f32x4 accs[2][2] = {{acc00, acc01}, {acc10, acc11}};
  for (int mt = 0; mt < 2; ++mt)
    for (int nt = 0; nt < 2; ++nt)
      for (int r = 0; r < 4; ++r) {
        int mrow = m0 + mb + mt * 16 + rb + r;
        int ncol = n0 + nb + nt * 16 + col;
        C[(size_t)mrow * ldc + ncol] = f2bf(accs[mt][nt][r]);
      }
}

// ---------------- stage B GEMM: all-bf16 internal --------------------------
__global__ __launch_bounds__(256) void gemm_bt(
    const u16* __restrict__ A,  int lda, long long sA,
    const u16* __restrict__ Bt, int ldb, long long sB,
    u16* __restrict__ C,        int ldc, long long sC,
    int K) {
  A  += (long long)blockIdx.z * sA;
  Bt += (long long)blockIdx.z * sB;
  C  += (long long)blockIdx.z * sC;
  const int m0 = blockIdx.y * 64, n0 = blockIdx.x * 64;
  __shared__ __align__(16) u16 As[64][72];
  __shared__ __align__(16) u16 Bs[64][72];
  const int tid  = threadIdx.x;
  const int lane = tid & 63, wave = tid >> 6;
  const int srow = tid >> 2, sseg = (tid & 3) * 8;
  const int mb = (wave & 1) * 32, nb = (wave >> 1) * 32;
  const int fr = lane & 15, koff = (lane >> 4) * 8;
  f32x4 z = {0.f, 0.f, 0.f, 0.f};
  f32x4 acc00 = z, acc01 = z, acc10 = z, acc11 = z;
  for (int k0 = 0; k0 < K; k0 += 32) {
    __syncthreads();
    *(uint4*)&As[srow][sseg] = *(const uint4*)&A[(size_t)(m0 + srow) * lda + k0 + sseg];
    *(uint4*)&Bs[srow][sseg] = *(const uint4*)&Bt[(size_t)(n0 + srow) * ldb + k0 + sseg];
    __syncthreads();
    bf16x8 a0 = *(const bf16x8*)&As[mb + fr][koff];
    bf16x8 a1 = *(const bf16x8*)&As[mb + 16 + fr][koff];
    bf16x8 b0 = *(const bf16x8*)&Bs[nb + fr][koff];
    bf16x8 b1 = *(const bf16x8*)&Bs[nb + 16 + fr][koff];
    acc00 = __builtin_amdgcn_mfma_f32_16x16x32_bf16(a0, b0, acc00, 0, 0, 0);
    acc01 = __builtin_amdgcn_mfma_f32_16x16x32_bf16(a0, b1, acc01, 0, 0, 0);
    acc10 = __builtin_amdgcn_mfma_f32_16x16x32_bf16(a1, b0, acc10, 0, 0, 0);
    acc11 = __builtin_amdgcn_mfma_f32_16x16x32_bf16(a1, b1, acc11, 0, 0, 0);
  }
  const int col = lane & 15, rb = (lane >> 4) * 4;
  f32x4 accs[2][2] = {{acc00, acc01}, {acc10, acc11}};
  for (int mt = 0; mt < 2; ++mt)
    for (int nt = 0; nt < 2; ++nt)
      for (int r = 0; r < 4; ++r) {
        int mrow = m0 + mb + mt * 16 + rb + r;
        int ncol = n0 + nb + nt * 16 + col;
        C[(size_t)mrow * ldc + ncol] = f2bf(accs[mt][nt][r]);
      }
}

// ---------------- stage C: per-mode 64ch complex contraction ----------------
__global__ __launch_bounds__(256) void modemix(
    const u16* __restrict__ P, const void* __restrict__ wre,
    const void* __restrict__ wim, u16* __restrict__ yt,
    const int* __restrict__ flag) {
  const int f32 = *flag;
  const int o = blockIdx.x >> 4;
  const int kxg = blockIdx.x & 15;
  const int tid = threadIdx.x;
  const int ky = tid & 63;
  const int kxj = tid >> 6;               // 0..3
  const int kx = kxg * 4 + kxj;
  float yR = 0.f, yI = 0.f;
  for (int i = 0; i < 64; ++i) {
    const u16* prow = P + i * 16384 + (2 * kx) * 128 + 2 * ky;
    unsigned p0 = *(const unsigned*)prow;          // [2kx][2ky], [2kx][2ky+1]
    unsigned p1 = *(const unsigned*)(prow + 128);  // [2kx+1][...]
    float p00 = bf2f((u16)(p0 & 0xFFFF)), p01 = bf2f((u16)(p0 >> 16));
    float p10 = bf2f((u16)(p1 & 0xFFFF)), p11 = bf2f((u16)(p1 >> 16));
    float xr = p00 - p11;
    float xi = p01 + p10;
    size_t widx = ((size_t)(i * 64 + o) * 64 + kx) * 64 + ky;
    float wr = rdx(wre, widx, f32);
    float wq = rdx(wim, widx, f32);
    yR += xr * wr - xi * wq;
    yI += xr * wq + xi * wr;
  }
  __shared__ u16 T[128][12];   // 24 B rows keep ushort4 (8 B) reads aligned
  T[2 * ky][2 * kxj]         = f2bf(yR);
  T[2 * ky][2 * kxj + 1]     = f2bf(yI);
  T[2 * ky + 1][2 * kxj]     = f2bf(yI);
  T[2 * ky + 1][2 * kxj + 1] = f2bf(-yR);
  __syncthreads();
  int r = tid >> 1, s = (tid & 1) * 4;
  u16* dst = yt + (size_t)o * 16384 + (size_t)r * 128 + kxg * 8 + s;
  ushort4 v;
  v.x = T[r][s]; v.y = T[r][s + 1]; v.z = T[r][s + 2]; v.w = T[r][s + 3];
  *(ushort4*)dst = v;
}

// ---------------- fused D+E: conv[o] stripe = (Gi @ yt[o]^T) @ Ct^T --------
// LDS stride 136 elems = 272 B = 17*16 (aligned b128).
__global__ __launch_bounds__(256) void inv_conv(
    const u16* __restrict__ Gi, const u16* __restrict__ Ct,
    const u16* __restrict__ yt, void* __restrict__ convV,
    const int* __restrict__ flag) {
  const int f32 = *flag;
  float* convF = (float*)convV;
  u16*   convH = (u16*)convV;
  const int m0 = blockIdx.x * 64;
  const int o  = blockIdx.y;
  __shared__ __align__(16) u16 lds[26112];   // 52 KB
  u16* As = lds;          // [64][136]  Gi tile;  later Cs (Ct tile)
  u16* Bs = lds + 8704;   // [128][136] yt;       later T [64][136]
  const int tid = threadIdx.x, lane = tid & 63, wave = tid >> 6;
  const int fr = lane & 15, koff = (lane >> 4) * 8;
  const int col = lane & 15, rb = (lane >> 4) * 4;
  {  // stage Gi tile (64x128)
    int r = tid >> 2, cs = (tid & 3) * 32;
    const u16* g = Gi + (size_t)(m0 + r) * 128 + cs;
    u16* d = As + r * 136 + cs;
#pragma unroll
    for (int j = 0; j < 4; ++j) *(uint4*)(d + 8 * j) = *(const uint4*)(g + 8 * j);
  }
  {  // stage full yt[o] (128x128)
    int r = tid >> 1, cs = (tid & 1) * 64;
    const u16* g = yt + (size_t)o * 16384 + (size_t)r * 128 + cs;
    u16* d = Bs + r * 136 + cs;
#pragma unroll
    for (int j = 0; j < 8; ++j) *(uint4*)(d + 8 * j) = *(const uint4*)(g + 8 * j);
  }
  __syncthreads();
  const int mb = (wave & 1) * 32, nh = (wave >> 1) * 64;
  f32x4 z = {0.f, 0.f, 0.f, 0.f};
  f32x4 acc1[2][4];
#pragma unroll
  for (int mt = 0; mt < 2; ++mt)
#pragma unroll
    for (int nt = 0; nt < 4; ++nt) acc1[mt][nt] = z;
  for (int k0 = 0; k0 < 128; k0 += 32) {
    bf16x8 a0 = *(const bf16x8*)(As + (mb + fr) * 136 + k0 + koff);
    bf16x8 a1 = *(const bf16x8*)(As + (mb + 16 + fr) * 136 + k0 + koff);
#pragma unroll
    for (int nt = 0; nt < 4; ++nt) {
      bf16x8 b = *(const bf16x8*)(Bs + (nh + nt * 16 + fr) * 136 + k0 + koff);
      acc1[0][nt] = __builtin_amdgcn_mfma_f32_16x16x32_bf16(a0, b, acc1[0][nt], 0, 0, 0);
      acc1[1][nt] = __builtin_amdgcn_mfma_f32_16x16x32_bf16(a1, b, acc1[1][nt], 0, 0, 0);
    }
  }
  __syncthreads();   // all As/Bs reads done before T overwrites Bs
  u16* T = Bs;       // [64][136], rows = m, cols = c
#pragma unroll
  for (int mt = 0; mt < 2; ++mt)
#pragma unroll
    for (int nt = 0; nt < 4; ++nt)
#pragma unroll
      for (int r = 0; r < 4; ++r)
        T[(mb + mt * 16 + rb + r) * 136 + nh + nt * 16 + col] = f2bf(acc1[mt][nt][r]);
  u16* Cs = lds;     // alias As
  const int mb2 = (wave & 1) * 32, nb2 = (wave >> 1) * 32;
  for (int nb0 = 0; nb0 < 8; ++nb0) {
    __syncthreads();
    {
      int r = tid >> 2, cs = (tid & 3) * 32;
      const u16* g = Ct + (size_t)(nb0 * 64 + r) * 128 + cs;
      u16* d = Cs + r * 136 + cs;
#pragma unroll
      for (int j = 0; j < 4; ++j) *(uint4*)(d + 8 * j) = *(const uint4*)(g + 8 * j);
    }
    __syncthreads();
    f32x4 acc2[2][2] = {{z, z}, {z, z}};
    for (int k0 = 0; k0 < 128; k0 += 32) {
      bf16x8 a0 = *(const bf16x8*)(T + (mb2 + fr) * 136 + k0 + koff);
      bf16x8 a1 = *(const bf16x8*)(T + (mb2 + 16 + fr) * 136 + k0 + koff);
      bf16x8 b0 = *(const bf16x8*)(Cs + (nb2 + fr) * 136 + k0 + koff);
      bf16x8 b1 = *(const bf16x8*)(Cs + (nb2 + 16 + fr) * 136 + k0 + koff);
      acc2[0][0] = __builtin_amdgcn_mfma_f32_16x16x32_bf16(a0, b0, acc2[0][0], 0, 0, 0);
      acc2[0][1] = __builtin_amdgcn_mfma_f32_16x16x32_bf16(a0, b1, acc2[0][1], 0, 0, 0);
      acc2[1][0] = __builtin_amdgcn_mfma_f32_16x16x32_bf16(a1, b0, acc2[1][0], 0, 0, 0);
      acc2[1][1] = __builtin_amdgcn_mfma_f32_16x16x32_bf16(a1, b1, acc2[1][1], 0, 0, 0);
    }
#pragma unroll
    for (int mt = 0; mt < 2; ++mt)
#pragma unroll
      for (int nt = 0; nt < 2; ++nt)
#pragma unroll
        for (int r = 0; r < 4; ++r) {
          size_t idx = (size_t)o * 262144 + (size_t)(m0 + mb2 + mt * 16 + rb + r) * 512
                     + nb0 * 64 + nb2 + nt * 16 + col;
          float v = acc2[mt][nt][r];
          if (f32) convF[idx] = v; else convH[idx] = f2bf(v);
        }
  }
}

// ---------------- stage F: MFMA skip GEMM + conv add + bias + gelu ---------
// out[o][p] = gelu(conv[o][p] + bias[o] + sum_i wbf[o][i]*x[i][p])
// Block: 256 px tile (all 64 o).  x tile transposed to LDS as bf16.
// LDS pad 72 (144 B = 9*16): b128 frag reads 2-way-conflict-free.
__global__ __launch_bounds__(256) void skip_final_mfma(
    const void* __restrict__ x, const u16* __restrict__ wbf,
    const float* __restrict__ bias, void* __restrict__ outV,
    const int* __restrict__ flag) {
  const int f32 = *flag;
  float* outF = (float*)outV;
  u16*   outH = (u16*)outV;
  const size_t p0 = (size_t)blockIdx.x * 256;
  __shared__ __align__(16) u16 As[64][72];    // w_skip: row o, col i
  __shared__ __align__(16) u16 Bs[256][72];   // x^T: row pixel, col i
  const int tid = threadIdx.x, lane = tid & 63, wave = tid >> 6;
  {  // stage w (8 KB)
    int r = tid >> 2, c0 = (tid & 3) * 16;
    *(uint4*)&As[r][c0]     = *(const uint4*)&wbf[r * 64 + c0];
    *(uint4*)&As[r][c0 + 8] = *(const uint4*)&wbf[r * 64 + c0 + 8];
  }
  {  // stage x tile transposed: thread t -> channel t>>2, pixels (t&3)*4 + 16j
    int ch = tid >> 2, quad = (tid & 3) * 4;
    if (f32) {
      const float* xp = (const float*)x + (size_t)ch * 262144 + p0 + quad;
#pragma unroll
      for (int j = 0; j < 16; ++j) {
        float4 v = *(const float4*)(xp + 16 * j);
        int p = quad + 16 * j;
        Bs[p + 0][ch] = f2bf(v.x); Bs[p + 1][ch] = f2bf(v.y);
        Bs[p + 2][ch] = f2bf(v.z); Bs[p + 3][ch] = f2bf(v.w);
      }
    } else {
      const u16* xp = (const u16*)x + (size_t)ch * 262144 + p0 + quad;
#pragma unroll
      for (int j = 0; j < 16; ++j) {
        ushort4 v = *(const ushort4*)(xp + 16 * j);
        int p = quad + 16 * j;
        Bs[p + 0][ch] = v.x; Bs[p + 1][ch] = v.y;
        Bs[p + 2][ch] = v.z; Bs[p + 3][ch] = v.w;
      }
    }
  }
  __syncthreads();
  // wave -> 64-pixel slice; M=64 (o) x N=64 (px) x K=64 per wave
  const int fr = lane & 15, koff = (lane >> 4) * 8;
  f32x4 z = {0.f, 0.f, 0.f, 0.f};
  f32x4 acc[4][4];   // [mi][ni]
#pragma unroll
  for (int mi = 0; mi < 4; ++mi)
#pragma unroll
    for (int ni = 0; ni < 4; ++ni) acc[mi][ni] = z;
#pragma unroll
  for (int k0 = 0; k0 < 64; k0 += 32) {
    bf16x8 a[4], b[4];
#pragma unroll
    for (int mi = 0; mi < 4; ++mi)
      a[mi] = *(const bf16x8*)&As[mi * 16 + fr][k0 + koff];
#pragma unroll
    for (int ni = 0; ni < 4; ++ni)
      b[ni] = *(const bf16x8*)&Bs[wave * 64 + ni * 16 + fr][k0 + koff];
#pragma unroll
    for (int mi = 0; mi < 4; ++mi)
#pragma unroll
      for (int ni = 0; ni < 4; ++ni)
        acc[mi][ni] = __builtin_amdgcn_mfma_f32_16x16x32_bf16(a[mi], b[ni], acc[mi][ni], 0, 0, 0);
  }
  // epilogue: conv add + bias + gelu, in place on d_out
  const int col = lane & 15, rb = (lane >> 4) * 4;
#pragma unroll
  for (int mi = 0; mi < 4; ++mi)
#pragma unroll
    for (int ni = 0; ni < 4; ++ni)
#pragma unroll
      for (int r = 0; r < 4; ++r) {
        int o = mi * 16 + rb + r;
        size_t idx = (size_t)o * 262144 + p0 + wave * 64 + ni * 16 + col;
        float cv = f32 ? outF[idx] : bf2f(outH[idx]);
        float v = acc[mi][ni][r] + cv + bias[o];
        // gelu(tanh approx) = v * sigmoid(2*0.7978845608*(v + 0.044715 v^3))
        float zz = 1.5957691216f * (v + 0.044715f * v * v * v);
        float g = v / (1.f + __expf(-zz));
        if (f32) outF[idx] = g; else outH[idx] = f2bf(g);
      }
}

extern "C" void kernel_launch(void* const* d_in, const int* in_sizes, int n_in,
                              void* d_out, int out_size, void* d_ws, size_t ws_size,
                              hipStream_t stream) {
  const void* x     = d_in[0];   // (64,512,512)
  const void* wre   = d_in[1];   // (64,64,64,64)
  const void* wim   = d_in[2];
  const void* bconv = d_in[3];   // (64,)
  const void* wskip = d_in[4];   // (64,64)
  const void* bskip = d_in[5];   // (64,)
  char* ws = (char*)d_ws;

  // ws layout (total 2.5 MB)
  u16*   EW   = (u16*)(ws);                            // 128 KB
  u16*   Gi   = (u16*)(ws + (1 << 17));                // 128 KB
  u16*   Ct   = (u16*)(ws + (2 << 17));                // 128 KB
  u16*   wbf  = (u16*)(ws + 3 * (1 << 17));            // 8 KB
  float* bias = (float*)(ws + 3 * (1 << 17) + 16384);  // 256 B
  int*   flag = (int*)(ws + 3 * (1 << 17) + 16640);    // 4 B
  u16*   yt   = (u16*)(ws + (1 << 19));                // 2 MB
  // d_out doubles as scratch before stage D+E (byte offsets; fits either dtype):
  u16* t1T = (u16*)d_out;                    // [0, 8MB):  64 x (128x512) bf16
  u16* P   = (u16*)((char*)d_out + (8 << 20));  // [8,10MB): 64 x (128x128) bf16

  sniff<<<1, 64, 0, stream>>>((const unsigned*)x, flag);
  init_tables<<<256, 256, 0, stream>>>(wskip, bconv, bskip, flag, EW, Gi, Ct, wbf, bias);
  // A: t1T[i](128x512) = EW @ x[i]^T        M=128 N=512 K=512, batch 64
  gemm_bt_x<<<dim3(8, 2, 64), 256, 0, stream>>>(EW, 512, x, 512, 262144, t1T, 512, 65536, 512, flag);
  // B: P[i](128x128) = EW @ t1T[i]^T        M=128 N=128 K=512
  gemm_bt<<<dim3(2, 2, 64), 256, 0, stream>>>(EW, 512, 0, t1T, 512, 65536, P, 128, 16384, 512);
  // C: mode mix -> yt[o] in ws (sym 2x2 layout)
  modemix<<<1024, 256, 0, stream>>>(P, wre, wim, yt, flag);
  // D+E fused: conv -> d_out (overwrites t1T/P scratch, both dead)
  inv_conv<<<dim3(8, 64), 256, 0, stream>>>(Gi, Ct, yt, d_out, flag);
  // F: MFMA skip + conv + bias + gelu (in-place on d_out)
  skip_final_mfma<<<1024, 256, 0, stream>>>(x, wbf, bias, d_out, flag);
}

// Round 3
// 301.644 us; speedup vs baseline: 1.0513x; 1.0258x over previous
//
#include <hip/hip_runtime.h>

// FourierLayer: rfft2 -> keep 64x64 modes -> per-mode channel mix -> irfft2
// + channelwise skip + gelu.  All DFTs collapse to dense GEMMs (only 64x64
// modes survive).  External dtype (fp32 vs bf16) is UNKNOWN -> detected at
// runtime by `sniff`.  Internal intermediates are always bf16.
//
// Memory plan:
//   ws:    EW/Gi/Ct/wbf/bias/flag tables (0.41 MB) + yt (2 MB)
//   d_out: phase1 t1T [0,8MB) -> phase2 P [8,10MB) -> conv (full, out dtype)
// Stages:
//   A: t1T[i](128x512) = EW(128x512) @ x[i](512x512)^T      (W-axis DFT)
//   B: P[i](128x128)   = EW(128x512) @ t1T[i]^T             (H-axis DFT)
//   C: yt[o](128x128)  = mode mix, sym 2x2 blocks [[yR,yI],[yI,-yR]] -> ws
//   D+E fused: conv[o] = (Gi @ yt[o]^T) @ Ct^T -> d_out
//   F: out = gelu(conv + bias + w_skip@x)  -- MFMA skip GEMM, in-place d_out
//      (R2 fix: register-transpose staging w/ ds_write_b64 + XOR swizzle,
//       128-px tile -> 27.6 KB LDS, 5 blocks/CU.  v1's 16K scalar u16 LDS
//       writes + 46 KB LDS were latency-bound at 21% occupancy.)

using bf16x8 = __attribute__((ext_vector_type(8))) short;
using f32x4  = __attribute__((ext_vector_type(4))) float;
typedef unsigned short u16;

__device__ __forceinline__ u16 f2bf(float f) {
  unsigned u = __float_as_uint(f);
  u = u + 0x7FFFu + ((u >> 16) & 1u);   // round-to-nearest-even
  return (u16)(u >> 16);
}
__device__ __forceinline__ float bf2f(u16 v) {
  return __uint_as_float(((unsigned)v) << 16);
}
// flag==1 -> externals are fp32; flag==0 -> externals are bf16
__device__ __forceinline__ float rdx(const void* p, size_t i, int f32) {
  return f32 ? ((const float*)p)[i] : bf2f(((const u16*)p)[i]);
}

// ---------------- dtype sniff ----------------------------------------------
__global__ void sniff(const unsigned* __restrict__ xw, int* __restrict__ flag) {
  unsigned u = xw[threadIdx.x];
  int e = (u >> 7) & 0xFF;                  // bf16-pair: exponent of low bf16
  unsigned long long m = __ballot(e >= 110 && e <= 130);
  if (threadIdx.x == 0) *flag = (__popcll(m) < 32) ? 1 : 0;   // 1 = fp32
}

// ---------------- twiddle tables + wskip bf16 + fused bias ------------------
__global__ __launch_bounds__(256) void init_tables(
    const void* __restrict__ wskip, const void* __restrict__ bconv,
    const void* __restrict__ bskip, const int* __restrict__ flag,
    u16* __restrict__ EW,    // [128][512]  fwd DFT (stages A and B)
    u16* __restrict__ Gi,    // [512][128]  inv DFT rows=h, cols=2kx|2kx+1
    u16* __restrict__ Ct,    // [512][128]  irfft rows=w
    u16* __restrict__ wbf,   // [o][i] skip weights, bf16 (MFMA A operand)
    float* __restrict__ bias) {
  const int f32 = *flag;
  int t = blockIdx.x * blockDim.x + threadIdx.x;   // 0..65535
  {
    // EW[m][n]: f=m>>1, part=m&1 -> part? -sin : cos of 2*pi*f*n/512
    int m = t >> 9, n = t & 511;
    int f = m >> 1, part = m & 1;
    int idx = (f * n) & 511;
    float ang = 0.01227184630308513f * (float)idx;  // 2*pi/512
    float s, c; __sincosf(ang, &s, &c);
    EW[t] = f2bf(part ? -s : c);
  }
  {
    int h = t >> 7, cc = t & 127;
    int f = cc >> 1, part = cc & 1;
    int idx = (f * h) & 511;
    float ang = 0.01227184630308513f * (float)idx;
    float s, c; __sincosf(ang, &s, &c);
    // inverse along H: e^{+i}/512 -> (cos, -sin) against [[yR,yI],[yI,-yR]]
    Gi[t] = f2bf((part ? -s : c) * (1.0f / 512.0f));
    // irfft along W: (1 if ky==0 else 2)/512 * (cos | -sin)
    float scale = (f == 0 ? 1.0f : 2.0f) * (1.0f / 512.0f);
    Ct[t] = f2bf((part ? -s : c) * scale);
  }
  if (t < 4096) wbf[t] = f2bf(rdx(wskip, t, f32));   // [o][i] row-major
  if (t < 64) bias[t] = rdx(bconv, t, f32) + rdx(bskip, t, f32);
}

// ---------------- stage A GEMM: B operand is the external x ----------------
// C[m][n] = sum_k A[m][k] * Bt[n][k];  blockIdx.z = batch (channel i).
// LDS row stride 72 elems = 144 B = 9*16 B (every b128 16B-aligned).
__global__ __launch_bounds__(256) void gemm_bt_x(
    const u16* __restrict__ A,  int lda,
    const void* __restrict__ BtV, int ldb, long long sB,
    u16* __restrict__ C,        int ldc, long long sC,
    int K, const int* __restrict__ flag) {
  const int f32 = *flag;
  const float* BtF = (const float*)BtV + (long long)blockIdx.z * sB;
  const u16*   BtH = (const u16*)BtV + (long long)blockIdx.z * sB;
  const int m0 = blockIdx.y * 64, n0 = blockIdx.x * 64;
  __shared__ __align__(16) u16 As[64][72];
  __shared__ __align__(16) u16 Bs[64][72];
  const int tid  = threadIdx.x;
  const int lane = tid & 63, wave = tid >> 6;
  const int srow = tid >> 2, sseg = (tid & 3) * 8;
  const int mb = (wave & 1) * 32, nb = (wave >> 1) * 32;
  const int fr = lane & 15, koff = (lane >> 4) * 8;
  f32x4 z = {0.f, 0.f, 0.f, 0.f};
  f32x4 acc00 = z, acc01 = z, acc10 = z, acc11 = z;
  for (int k0 = 0; k0 < K; k0 += 32) {
    __syncthreads();
    *(uint4*)&As[srow][sseg] = *(const uint4*)&A[(size_t)(m0 + srow) * lda + k0 + sseg];
    size_t bofs = (size_t)(n0 + srow) * ldb + k0 + sseg;
    if (f32) {
      float4 u = *(const float4*)(BtF + bofs);
      float4 v = *(const float4*)(BtF + bofs + 4);
      uint4 w;
      w.x = (unsigned)f2bf(u.x) | ((unsigned)f2bf(u.y) << 16);
      w.y = (unsigned)f2bf(u.z) | ((unsigned)f2bf(u.w) << 16);
      w.z = (unsigned)f2bf(v.x) | ((unsigned)f2bf(v.y) << 16);
      w.w = (unsigned)f2bf(v.z) | ((unsigned)f2bf(v.w) << 16);
      *(uint4*)&Bs[srow][sseg] = w;
    } else {
      *(uint4*)&Bs[srow][sseg] = *(const uint4*)(BtH + bofs);
    }
    __syncthreads();
    bf16x8 a0 = *(const bf16x8*)&As[mb + fr][koff];
    bf16x8 a1 = *(const bf16x8*)&As[mb + 16 + fr][koff];
    bf16x8 b0 = *(const bf16x8*)&Bs[nb + fr][koff];
    bf16x8 b1 = *(const bf16x8*)&Bs[nb + 16 + fr][koff];
    acc00 = __builtin_amdgcn_mfma_f32_16x16x32_bf16(a0, b0, acc00, 0, 0, 0);
    acc01 = __builtin_amdgcn_mfma_f32_16x16x32_bf16(a0, b1, acc01, 0, 0, 0);
    acc10 = __builtin_amdgcn_mfma_f32_16x16x32_bf16(a1, b0, acc10, 0, 0, 0);
    acc11 = __builtin_amdgcn_mfma_f32_16x16x32_bf16(a1, b1, acc11, 0, 0, 0);
  }
  // C/D layout: col = lane&15, row = (lane>>4)*4 + reg
  const int col = lane & 15, rb = (lane >> 4) * 4;
  f32x4 accs[2][2] = {{acc00, acc01}, {acc10, acc11}};
  for (int mt = 0; mt < 2; ++mt)
    for (int nt = 0; nt < 2; ++nt)
      for (int r = 0; r < 4; ++r) {
        int mrow = m0 + mb + mt * 16 + rb + r;
        int ncol = n0 + nb + nt * 16 + col;
        C[(size_t)mrow * ldc + ncol] = f2bf(accs[mt][nt][r]);
      }
}

// ---------------- stage B GEMM: all-bf16 internal --------------------------
__global__ __launch_bounds__(256) void gemm_bt(
    const u16* __restrict__ A,  int lda, long long sA,
    const u16* __restrict__ Bt, int ldb, long long sB,
    u16* __restrict__ C,        int ldc, long long sC,
    int K) {
  A  += (long long)blockIdx.z * sA;
  Bt += (long long)blockIdx.z * sB;
  C  += (long long)blockIdx.z * sC;
  const int m0 = blockIdx.y * 64, n0 = blockIdx.x * 64;
  __shared__ __align__(16) u16 As[64][72];
  __shared__ __align__(16) u16 Bs[64][72];
  const int tid  = threadIdx.x;
  const int lane = tid & 63, wave = tid >> 6;
  const int srow = tid >> 2, sseg = (tid & 3) * 8;
  const int mb = (wave & 1) * 32, nb = (wave >> 1) * 32;
  const int fr = lane & 15, koff = (lane >> 4) * 8;
  f32x4 z = {0.f, 0.f, 0.f, 0.f};
  f32x4 acc00 = z, acc01 = z, acc10 = z, acc11 = z;
  for (int k0 = 0; k0 < K; k0 += 32) {
    __syncthreads();
    *(uint4*)&As[srow][sseg] = *(const uint4*)&A[(size_t)(m0 + srow) * lda + k0 + sseg];
    *(uint4*)&Bs[srow][sseg] = *(const uint4*)&Bt[(size_t)(n0 + srow) * ldb + k0 + sseg];
    __syncthreads();
    bf16x8 a0 = *(const bf16x8*)&As[mb + fr][koff];
    bf16x8 a1 = *(const bf16x8*)&As[mb + 16 + fr][koff];
    bf16x8 b0 = *(const bf16x8*)&Bs[nb + fr][koff];
    bf16x8 b1 = *(const bf16x8*)&Bs[nb + 16 + fr][koff];
    acc00 = __builtin_amdgcn_mfma_f32_16x16x32_bf16(a0, b0, acc00, 0, 0, 0);
    acc01 = __builtin_amdgcn_mfma_f32_16x16x32_bf16(a0, b1, acc01, 0, 0, 0);
    acc10 = __builtin_amdgcn_mfma_f32_16x16x32_bf16(a1, b0, acc10, 0, 0, 0);
    acc11 = __builtin_amdgcn_mfma_f32_16x16x32_bf16(a1, b1, acc11, 0, 0, 0);
  }
  const int col = lane & 15, rb = (lane >> 4) * 4;
  f32x4 accs[2][2] = {{acc00, acc01}, {acc10, acc11}};
  for (int mt = 0; mt < 2; ++mt)
    for (int nt = 0; nt < 2; ++nt)
      for (int r = 0; r < 4; ++r) {
        int mrow = m0 + mb + mt * 16 + rb + r;
        int ncol = n0 + nb + nt * 16 + col;
        C[(size_t)mrow * ldc + ncol] = f2bf(accs[mt][nt][r]);
      }
}

// ---------------- stage C: per-mode 64ch complex contraction ----------------
__global__ __launch_bounds__(256) void modemix(
    const u16* __restrict__ P, const void* __restrict__ wre,
    const void* __restrict__ wim, u16* __restrict__ yt,
    const int* __restrict__ flag) {
  const int f32 = *flag;
  const int o = blockIdx.x >> 4;
  const int kxg = blockIdx.x & 15;
  const int tid = threadIdx.x;
  const int ky = tid & 63;
  const int kxj = tid >> 6;               // 0..3
  const int kx = kxg * 4 + kxj;
  float yR = 0.f, yI = 0.f;
  for (int i = 0; i < 64; ++i) {
    const u16* prow = P + i * 16384 + (2 * kx) * 128 + 2 * ky;
    unsigned p0 = *(const unsigned*)prow;          // [2kx][2ky], [2kx][2ky+1]
    unsigned p1 = *(const unsigned*)(prow + 128);  // [2kx+1][...]
    float p00 = bf2f((u16)(p0 & 0xFFFF)), p01 = bf2f((u16)(p0 >> 16));
    float p10 = bf2f((u16)(p1 & 0xFFFF)), p11 = bf2f((u16)(p1 >> 16));
    float xr = p00 - p11;
    float xi = p01 + p10;
    size_t widx = ((size_t)(i * 64 + o) * 64 + kx) * 64 + ky;
    float wr = rdx(wre, widx, f32);
    float wq = rdx(wim, widx, f32);
    yR += xr * wr - xi * wq;
    yI += xr * wq + xi * wr;
  }
  __shared__ u16 T[128][12];   // 24 B rows keep ushort4 (8 B) reads aligned
  T[2 * ky][2 * kxj]         = f2bf(yR);
  T[2 * ky][2 * kxj + 1]     = f2bf(yI);
  T[2 * ky + 1][2 * kxj]     = f2bf(yI);
  T[2 * ky + 1][2 * kxj + 1] = f2bf(-yR);
  __syncthreads();
  int r = tid >> 1, s = (tid & 1) * 4;
  u16* dst = yt + (size_t)o * 16384 + (size_t)r * 128 + kxg * 8 + s;
  ushort4 v;
  v.x = T[r][s]; v.y = T[r][s + 1]; v.z = T[r][s + 2]; v.w = T[r][s + 3];
  *(ushort4*)dst = v;
}

// ---------------- fused D+E: conv[o] stripe = (Gi @ yt[o]^T) @ Ct^T --------
// LDS stride 136 elems = 272 B = 17*16 (aligned b128).
__global__ __launch_bounds__(256) void inv_conv(
    const u16* __restrict__ Gi, const u16* __restrict__ Ct,
    const u16* __restrict__ yt, void* __restrict__ convV,
    const int* __restrict__ flag) {
  const int f32 = *flag;
  float* convF = (float*)convV;
  u16*   convH = (u16*)convV;
  const int m0 = blockIdx.x * 64;
  const int o  = blockIdx.y;
  __shared__ __align__(16) u16 lds[26112];   // 52 KB
  u16* As = lds;          // [64][136]  Gi tile;  later Cs (Ct tile)
  u16* Bs = lds + 8704;   // [128][136] yt;       later T [64][136]
  const int tid = threadIdx.x, lane = tid & 63, wave = tid >> 6;
  const int fr = lane & 15, koff = (lane >> 4) * 8;
  const int col = lane & 15, rb = (lane >> 4) * 4;
  {  // stage Gi tile (64x128)
    int r = tid >> 2, cs = (tid & 3) * 32;
    const u16* g = Gi + (size_t)(m0 + r) * 128 + cs;
    u16* d = As + r * 136 + cs;
#pragma unroll
    for (int j = 0; j < 4; ++j) *(uint4*)(d + 8 * j) = *(const uint4*)(g + 8 * j);
  }
  {  // stage full yt[o] (128x128)
    int r = tid >> 1, cs = (tid & 1) * 64;
    const u16* g = yt + (size_t)o * 16384 + (size_t)r * 128 + cs;
    u16* d = Bs + r * 136 + cs;
#pragma unroll
    for (int j = 0; j < 8; ++j) *(uint4*)(d + 8 * j) = *(const uint4*)(g + 8 * j);
  }
  __syncthreads();
  const int mb = (wave & 1) * 32, nh = (wave >> 1) * 64;
  f32x4 z = {0.f, 0.f, 0.f, 0.f};
  f32x4 acc1[2][4];
#pragma unroll
  for (int mt = 0; mt < 2; ++mt)
#pragma unroll
    for (int nt = 0; nt < 4; ++nt) acc1[mt][nt] = z;
  for (int k0 = 0; k0 < 128; k0 += 32) {
    bf16x8 a0 = *(const bf16x8*)(As + (mb + fr) * 136 + k0 + koff);
    bf16x8 a1 = *(const bf16x8*)(As + (mb + 16 + fr) * 136 + k0 + koff);
#pragma unroll
    for (int nt = 0; nt < 4; ++nt) {
      bf16x8 b = *(const bf16x8*)(Bs + (nh + nt * 16 + fr) * 136 + k0 + koff);
      acc1[0][nt] = __builtin_amdgcn_mfma_f32_16x16x32_bf16(a0, b, acc1[0][nt], 0, 0, 0);
      acc1[1][nt] = __builtin_amdgcn_mfma_f32_16x16x32_bf16(a1, b, acc1[1][nt], 0, 0, 0);
    }
  }
  __syncthreads();   // all As/Bs reads done before T overwrites Bs
  u16* T = Bs;       // [64][136], rows = m, cols = c
#pragma unroll
  for (int mt = 0; mt < 2; ++mt)
#pragma unroll
    for (int nt = 0; nt < 4; ++nt)
#pragma unroll
      for (int r = 0; r < 4; ++r)
        T[(mb + mt * 16 + rb + r) * 136 + nh + nt * 16 + col] = f2bf(acc1[mt][nt][r]);
  u16* Cs = lds;     // alias As
  const int mb2 = (wave & 1) * 32, nb2 = (wave >> 1) * 32;
  for (int nb0 = 0; nb0 < 8; ++nb0) {
    __syncthreads();
    {
      int r = tid >> 2, cs = (tid & 3) * 32;
      const u16* g = Ct + (size_t)(nb0 * 64 + r) * 128 + cs;
      u16* d = Cs + r * 136 + cs;
#pragma unroll
      for (int j = 0; j < 4; ++j) *(uint4*)(d + 8 * j) = *(const uint4*)(g + 8 * j);
    }
    __syncthreads();
    f32x4 acc2[2][2] = {{z, z}, {z, z}};
    for (int k0 = 0; k0 < 128; k0 += 32) {
      bf16x8 a0 = *(const bf16x8*)(T + (mb2 + fr) * 136 + k0 + koff);
      bf16x8 a1 = *(const bf16x8*)(T + (mb2 + 16 + fr) * 136 + k0 + koff);
      bf16x8 b0 = *(const bf16x8*)(Cs + (nb2 + fr) * 136 + k0 + koff);
      bf16x8 b1 = *(const bf16x8*)(Cs + (nb2 + 16 + fr) * 136 + k0 + koff);
      acc2[0][0] = __builtin_amdgcn_mfma_f32_16x16x32_bf16(a0, b0, acc2[0][0], 0, 0, 0);
      acc2[0][1] = __builtin_amdgcn_mfma_f32_16x16x32_bf16(a0, b1, acc2[0][1], 0, 0, 0);
      acc2[1][0] = __builtin_amdgcn_mfma_f32_16x16x32_bf16(a1, b0, acc2[1][0], 0, 0, 0);
      acc2[1][1] = __builtin_amdgcn_mfma_f32_16x16x32_bf16(a1, b1, acc2[1][1], 0, 0, 0);
    }
#pragma unroll
    for (int mt = 0; mt < 2; ++mt)
#pragma unroll
      for (int nt = 0; nt < 2; ++nt)
#pragma unroll
        for (int r = 0; r < 4; ++r) {
          size_t idx = (size_t)o * 262144 + (size_t)(m0 + mb2 + mt * 16 + rb + r) * 512
                     + nb0 * 64 + nb2 + nt * 16 + col;
          float v = acc2[mt][nt][r];
          if (f32) convF[idx] = v; else convH[idx] = f2bf(v);
        }
  }
}

// ---------------- stage F: MFMA skip GEMM + conv add + bias + gelu ---------
// out[o][p] = gelu(conv[o][p] + bias[o] + sum_i wbf[o][i]*x[i][p])
// Block: 128 px tile, all 64 o.  Grid 2048.  LDS 27.6 KB -> 5 blocks/CU.
// Staging: register transpose (4ch x 4px per thread), ds_write_b64, XOR
// swizzle on channel column (granule 8 ch = b128 read width).
__global__ __launch_bounds__(256) void skip_final_mfma(
    const void* __restrict__ x, const u16* __restrict__ wbf,
    const float* __restrict__ bias, void* __restrict__ outV,
    const int* __restrict__ flag) {
  const int f32 = *flag;
  float* outF = (float*)outV;
  u16*   outH = (u16*)outV;
  const size_t p0 = (size_t)blockIdx.x * 128;
  __shared__ __align__(16) u16 As[64][72];    // w_skip: row o, col i
  __shared__ __align__(16) u16 Bs[128][72];   // x^T: row px, col ch (swizzled)
  const int tid = threadIdx.x, lane = tid & 63, wave = tid >> 6;
  {  // stage w (8 KB)
    int r = tid >> 2, c0 = (tid & 3) * 16;
    *(uint4*)&As[r][c0]     = *(const uint4*)&wbf[r * 64 + c0];
    *(uint4*)&As[r][c0 + 8] = *(const uint4*)&wbf[r * 64 + c0 + 8];
  }
  {  // stage x^T: 2 iters of (64 px x 64 ch); thread: 4 ch x 4 px reg-transpose
    const int cq = tid >> 4;          // 0..15 -> channels cq*4..+3
    const int pq = tid & 15;          // 0..15 -> px quad
    const int c0 = cq * 4;
    for (int ib = 0; ib < 2; ++ib) {
      const int px = ib * 64 + pq * 4;
      u16 v[4][4];   // [j ch][k px]
      if (f32) {
        const float* xp = (const float*)x + p0 + px;
#pragma unroll
        for (int j = 0; j < 4; ++j) {
          float4 t = *(const float4*)(xp + (size_t)(c0 + j) * 262144);
          v[j][0] = f2bf(t.x); v[j][1] = f2bf(t.y);
          v[j][2] = f2bf(t.z); v[j][3] = f2bf(t.w);
        }
      } else {
        const u16* xp = (const u16*)x + p0 + px;
#pragma unroll
        for (int j = 0; j < 4; ++j) {
          ushort4 t = *(const ushort4*)(xp + (size_t)(c0 + j) * 262144);
          v[j][0] = t.x; v[j][1] = t.y; v[j][2] = t.z; v[j][3] = t.w;
        }
      }
#pragma unroll
      for (int k = 0; k < 4; ++k) {
        int row = px + k;
        int cs = c0 ^ (((row >> 2) & 7) << 3);   // swizzled channel col
        ushort4 w4;
        w4.x = v[0][k]; w4.y = v[1][k]; w4.z = v[2][k]; w4.w = v[3][k];
        *(ushort4*)&Bs[row][cs] = w4;
      }
    }
  }
  __syncthreads();
  // wave -> 32-px slice; per wave M=64 (o) x N=32 (px) x K=64
  const int fr = lane & 15, koff = (lane >> 4) * 8;
  f32x4 z = {0.f, 0.f, 0.f, 0.f};
  f32x4 acc[4][2];   // [mi][ni]
#pragma unroll
  for (int mi = 0; mi < 4; ++mi)
#pragma unroll
    for (int ni = 0; ni < 2; ++ni) acc[mi][ni] = z;
#pragma unroll
  for (int k0 = 0; k0 < 64; k0 += 32) {
    bf16x8 a[4], b[2];
#pragma unroll
    for (int mi = 0; mi < 4; ++mi)
      a[mi] = *(const bf16x8*)&As[mi * 16 + fr][k0 + koff];
#pragma unroll
    for (int ni = 0; ni < 2; ++ni) {
      int prow = wave * 32 + ni * 16 + fr;
      int sw = ((prow >> 2) & 7) << 3;
      b[ni] = *(const bf16x8*)&Bs[prow][(k0 + koff) ^ sw];
    }
#pragma unroll
    for (int mi = 0; mi < 4; ++mi)
#pragma unroll
      for (int ni = 0; ni < 2; ++ni)
        acc[mi][ni] = __builtin_amdgcn_mfma_f32_16x16x32_bf16(a[mi], b[ni], acc[mi][ni], 0, 0, 0);
  }
  // epilogue: conv add + bias + gelu, in place on d_out
  const int col = lane & 15, rb = (lane >> 4) * 4;
#pragma unroll
  for (int mi = 0; mi < 4; ++mi)
#pragma unroll
    for (int ni = 0; ni < 2; ++ni)
#pragma unroll
      for (int r = 0; r < 4; ++r) {
        int o = mi * 16 + rb + r;
        size_t idx = (size_t)o * 262144 + p0 + wave * 32 + ni * 16 + col;
        float cv = f32 ? outF[idx] : bf2f(outH[idx]);
        float v = acc[mi][ni][r] + cv + bias[o];
        // gelu(tanh approx) = v * sigmoid(2*0.7978845608*(v + 0.044715 v^3))
        float zz = 1.5957691216f * (v + 0.044715f * v * v * v);
        float g = v / (1.f + __expf(-zz));
        if (f32) outF[idx] = g; else outH[idx] = f2bf(g);
      }
}

extern "C" void kernel_launch(void* const* d_in, const int* in_sizes, int n_in,
                              void* d_out, int out_size, void* d_ws, size_t ws_size,
                              hipStream_t stream) {
  const void* x     = d_in[0];   // (64,512,512)
  const void* wre   = d_in[1];   // (64,64,64,64)
  const void* wim   = d_in[2];
  const void* bconv = d_in[3];   // (64,)
  const void* wskip = d_in[4];   // (64,64)
  const void* bskip = d_in[5];   // (64,)
  char* ws = (char*)d_ws;

  // ws layout (total 2.5 MB)
  u16*   EW   = (u16*)(ws);                            // 128 KB
  u16*   Gi   = (u16*)(ws + (1 << 17));                // 128 KB
  u16*   Ct   = (u16*)(ws + (2 << 17));                // 128 KB
  u16*   wbf  = (u16*)(ws + 3 * (1 << 17));            // 8 KB
  float* bias = (float*)(ws + 3 * (1 << 17) + 16384);  // 256 B
  int*   flag = (int*)(ws + 3 * (1 << 17) + 16640);    // 4 B
  u16*   yt   = (u16*)(ws + (1 << 19));                // 2 MB
  // d_out doubles as scratch before stage D+E (byte offsets; fits either dtype):
  u16* t1T = (u16*)d_out;                    // [0, 8MB):  64 x (128x512) bf16
  u16* P   = (u16*)((char*)d_out + (8 << 20));  // [8,10MB): 64 x (128x128) bf16

  sniff<<<1, 64, 0, stream>>>((const unsigned*)x, flag);
  init_tables<<<256, 256, 0, stream>>>(wskip, bconv, bskip, flag, EW, Gi, Ct, wbf, bias);
  // A: t1T[i](128x512) = EW @ x[i]^T        M=128 N=512 K=512, batch 64
  gemm_bt_x<<<dim3(8, 2, 64), 256, 0, stream>>>(EW, 512, x, 512, 262144, t1T, 512, 65536, 512, flag);
  // B: P[i](128x128) = EW @ t1T[i]^T        M=128 N=128 K=512
  gemm_bt<<<dim3(2, 2, 64), 256, 0, stream>>>(EW, 512, 0, t1T, 512, 65536, P, 128, 16384, 512);
  // C: mode mix -> yt[o] in ws (sym 2x2 layout)
  modemix<<<1024, 256, 0, stream>>>(P, wre, wim, yt, flag);
  // D+E fused: conv -> d_out (overwrites t1T/P scratch, both dead)
  inv_conv<<<dim3(8, 64), 256, 0, stream>>>(Gi, Ct, yt, d_out, flag);
  // F: MFMA skip + conv + bias + gelu (in-place on d_out)
  skip_final_mfma<<<2048, 256, 0, stream>>>(x, wbf, bias, d_out, flag);
}

// Round 4
// 299.557 us; speedup vs baseline: 1.0587x; 1.0070x over previous
//
#include <hip/hip_runtime.h>

// FourierLayer: rfft2 -> keep 64x64 modes -> per-mode channel mix -> irfft2
// + channelwise skip + gelu.  All DFTs collapse to dense GEMMs (only 64x64
// modes survive).  External dtype (fp32 vs bf16) is UNKNOWN -> detected at
// runtime by `sniff`.  Internal intermediates are always bf16.
//
// Memory plan:
//   ws:    EW/Gi/Ct/wbf/bias/flag tables (0.41 MB) + yt (2 MB)
//   d_out: phase1 t1T [0,8MB) -> phase2 P [8,10MB) -> conv (full, out dtype)
// Stages:
//   A: t1T[i](128x512) = EW(128x512) @ x[i](512x512)^T      (W-axis DFT)
//      (R3: 512-thread blocks, full M=128 per n-tile -> x fetched ONCE)
//   B: P[i](128x128)   = EW(128x512) @ t1T[i]^T             (H-axis DFT)
//   C: yt[o](128x128)  = mode mix, sym 2x2 blocks [[yR,yI],[yI,-yR]] -> ws
//   D+E fused: conv[o] = (Gi @ yt[o]^T) @ Ct^T -> d_out
//   F: out = gelu(conv + bias + w_skip@x)  -- MFMA skip GEMM, in-place d_out
//      (R3: w-fragments direct from global (8KB L1-hot), no As LDS ->
//       18.4 KB LDS, launch_bounds(256,6).  R2's 5-block residency + VGPR=44
//       couldn't batch the 32 scattered conv RMWs -> latency-bound at 62us.)

using bf16x8 = __attribute__((ext_vector_type(8))) short;
using f32x4  = __attribute__((ext_vector_type(4))) float;
typedef unsigned short u16;

__device__ __forceinline__ u16 f2bf(float f) {
  unsigned u = __float_as_uint(f);
  u = u + 0x7FFFu + ((u >> 16) & 1u);   // round-to-nearest-even
  return (u16)(u >> 16);
}
__device__ __forceinline__ float bf2f(u16 v) {
  return __uint_as_float(((unsigned)v) << 16);
}
// flag==1 -> externals are fp32; flag==0 -> externals are bf16
__device__ __forceinline__ float rdx(const void* p, size_t i, int f32) {
  return f32 ? ((const float*)p)[i] : bf2f(((const u16*)p)[i]);
}

// ---------------- dtype sniff ----------------------------------------------
__global__ void sniff(const unsigned* __restrict__ xw, int* __restrict__ flag) {
  unsigned u = xw[threadIdx.x];
  int e = (u >> 7) & 0xFF;                  // bf16-pair: exponent of low bf16
  unsigned long long m = __ballot(e >= 110 && e <= 130);
  if (threadIdx.x == 0) *flag = (__popcll(m) < 32) ? 1 : 0;   // 1 = fp32
}

// ---------------- twiddle tables + wskip bf16 + fused bias ------------------
__global__ __launch_bounds__(256) void init_tables(
    const void* __restrict__ wskip, const void* __restrict__ bconv,
    const void* __restrict__ bskip, const int* __restrict__ flag,
    u16* __restrict__ EW,    // [128][512]  fwd DFT (stages A and B)
    u16* __restrict__ Gi,    // [512][128]  inv DFT rows=h, cols=2kx|2kx+1
    u16* __restrict__ Ct,    // [512][128]  irfft rows=w
    u16* __restrict__ wbf,   // [o][i] skip weights, bf16 (MFMA A operand)
    float* __restrict__ bias) {
  const int f32 = *flag;
  int t = blockIdx.x * blockDim.x + threadIdx.x;   // 0..65535
  {
    // EW[m][n]: f=m>>1, part=m&1 -> part? -sin : cos of 2*pi*f*n/512
    int m = t >> 9, n = t & 511;
    int f = m >> 1, part = m & 1;
    int idx = (f * n) & 511;
    float ang = 0.01227184630308513f * (float)idx;  // 2*pi/512
    float s, c; __sincosf(ang, &s, &c);
    EW[t] = f2bf(part ? -s : c);
  }
  {
    int h = t >> 7, cc = t & 127;
    int f = cc >> 1, part = cc & 1;
    int idx = (f * h) & 511;
    float ang = 0.01227184630308513f * (float)idx;
    float s, c; __sincosf(ang, &s, &c);
    // inverse along H: e^{+i}/512 -> (cos, -sin) against [[yR,yI],[yI,-yR]]
    Gi[t] = f2bf((part ? -s : c) * (1.0f / 512.0f));
    // irfft along W: (1 if ky==0 else 2)/512 * (cos | -sin)
    float scale = (f == 0 ? 1.0f : 2.0f) * (1.0f / 512.0f);
    Ct[t] = f2bf((part ? -s : c) * scale);
  }
  if (t < 4096) wbf[t] = f2bf(rdx(wskip, t, f32));   // [o][i] row-major
  if (t < 64) bias[t] = rdx(bconv, t, f32) + rdx(bskip, t, f32);
}

// ---------------- stage A GEMM: B operand is the external x ----------------
// C[m][n] = sum_k A[m][k] * Bt[n][k];  blockIdx.z = batch (channel i).
// 512 threads, full M=128 x N=64 per block: every x tile fetched once.
// LDS row stride 72 elems = 144 B = 9*16 B (every b128 16B-aligned).
__global__ __launch_bounds__(512) void gemm_bt_x(
    const u16* __restrict__ A,  int lda,
    const void* __restrict__ BtV, int ldb, long long sB,
    u16* __restrict__ C,        int ldc, long long sC,
    int K, const int* __restrict__ flag) {
  const int f32 = *flag;
  const float* BtF = (const float*)BtV + (long long)blockIdx.z * sB;
  const u16*   BtH = (const u16*)BtV + (long long)blockIdx.z * sB;
  C += (long long)blockIdx.z * sC;
  const int n0 = blockIdx.x * 64;
  __shared__ __align__(16) u16 As[128][72];   // 18.4 KB
  __shared__ __align__(16) u16 Bs[64][72];    //  9.2 KB
  const int tid  = threadIdx.x;
  const int lane = tid & 63, wave = tid >> 6;        // 8 waves
  const int srowA = tid >> 2, ssegA = (tid & 3) * 8; // 128 rows x 32 cols
  const int srowB = tid >> 3, ssegB = (tid & 7) * 4; //  64 rows x 32 cols
  const int mb = (wave & 3) * 32, nb = (wave >> 2) * 32;
  const int fr = lane & 15, koff = (lane >> 4) * 8;
  f32x4 z = {0.f, 0.f, 0.f, 0.f};
  f32x4 acc00 = z, acc01 = z, acc10 = z, acc11 = z;
  for (int k0 = 0; k0 < K; k0 += 32) {
    __syncthreads();
    *(uint4*)&As[srowA][ssegA] = *(const uint4*)&A[(size_t)srowA * lda + k0 + ssegA];
    size_t bofs = (size_t)(n0 + srowB) * ldb + k0 + ssegB;
    if (f32) {
      float4 u = *(const float4*)(BtF + bofs);
      ushort4 w;
      w.x = f2bf(u.x); w.y = f2bf(u.y); w.z = f2bf(u.z); w.w = f2bf(u.w);
      *(ushort4*)&Bs[srowB][ssegB] = w;
    } else {
      *(ushort4*)&Bs[srowB][ssegB] = *(const ushort4*)(BtH + bofs);
    }
    __syncthreads();
    bf16x8 a0 = *(const bf16x8*)&As[mb + fr][koff];
    bf16x8 a1 = *(const bf16x8*)&As[mb + 16 + fr][koff];
    bf16x8 b0 = *(const bf16x8*)&Bs[nb + fr][koff];
    bf16x8 b1 = *(const bf16x8*)&Bs[nb + 16 + fr][koff];
    acc00 = __builtin_amdgcn_mfma_f32_16x16x32_bf16(a0, b0, acc00, 0, 0, 0);
    acc01 = __builtin_amdgcn_mfma_f32_16x16x32_bf16(a0, b1, acc01, 0, 0, 0);
    acc10 = __builtin_amdgcn_mfma_f32_16x16x32_bf16(a1, b0, acc10, 0, 0, 0);
    acc11 = __builtin_amdgcn_mfma_f32_16x16x32_bf16(a1, b1, acc11, 0, 0, 0);
  }
  // C/D layout: col = lane&15, row = (lane>>4)*4 + reg
  const int col = lane & 15, rb = (lane >> 4) * 4;
  f32x4 accs[2][2] = {{acc00, acc01}, {acc10, acc11}};
  for (int mt = 0; mt < 2; ++mt)
    for (int nt = 0; nt < 2; ++nt)
      for (int r = 0; r < 4; ++r) {
        int mrow = mb + mt * 16 + rb + r;
        int ncol = n0 + nb + nt * 16 + col;
        C[(size_t)mrow * ldc + ncol] = f2bf(accs[mt][nt][r]);
      }
}

// ---------------- stage B GEMM: all-bf16 internal --------------------------
__global__ __launch_bounds__(256) void gemm_bt(
    const u16* __restrict__ A,  int lda, long long sA,
    const u16* __restrict__ Bt, int ldb, long long sB,
    u16* __restrict__ C,        int ldc, long long sC,
    int K) {
  A  += (long long)blockIdx.z * sA;
  Bt += (long long)blockIdx.z * sB;
  C  += (long long)blockIdx.z * sC;
  const int m0 = blockIdx.y * 64, n0 = blockIdx.x * 64;
  __shared__ __align__(16) u16 As[64][72];
  __shared__ __align__(16) u16 Bs[64][72];
  const int tid  = threadIdx.x;
  const int lane = tid & 63, wave = tid >> 6;
  const int srow = tid >> 2, sseg = (tid & 3) * 8;
  const int mb = (wave & 1) * 32, nb = (wave >> 1) * 32;
  const int fr = lane & 15, koff = (lane >> 4) * 8;
  f32x4 z = {0.f, 0.f, 0.f, 0.f};
  f32x4 acc00 = z, acc01 = z, acc10 = z, acc11 = z;
  for (int k0 = 0; k0 < K; k0 += 32) {
    __syncthreads();
    *(uint4*)&As[srow][sseg] = *(const uint4*)&A[(size_t)(m0 + srow) * lda + k0 + sseg];
    *(uint4*)&Bs[srow][sseg] = *(const uint4*)&Bt[(size_t)(n0 + srow) * ldb + k0 + sseg];
    __syncthreads();
    bf16x8 a0 = *(const bf16x8*)&As[mb + fr][koff];
    bf16x8 a1 = *(const bf16x8*)&As[mb + 16 + fr][koff];
    bf16x8 b0 = *(const bf16x8*)&Bs[nb + fr][koff];
    bf16x8 b1 = *(const bf16x8*)&Bs[nb + 16 + fr][koff];
    acc00 = __builtin_amdgcn_mfma_f32_16x16x32_bf16(a0, b0, acc00, 0, 0, 0);
    acc01 = __builtin_amdgcn_mfma_f32_16x16x32_bf16(a0, b1, acc01, 0, 0, 0);
    acc10 = __builtin_amdgcn_mfma_f32_16x16x32_bf16(a1, b0, acc10, 0, 0, 0);
    acc11 = __builtin_amdgcn_mfma_f32_16x16x32_bf16(a1, b1, acc11, 0, 0, 0);
  }
  const int col = lane & 15, rb = (lane >> 4) * 4;
  f32x4 accs[2][2] = {{acc00, acc01}, {acc10, acc11}};
  for (int mt = 0; mt < 2; ++mt)
    for (int nt = 0; nt < 2; ++nt)
      for (int r = 0; r < 4; ++r) {
        int mrow = m0 + mb + mt * 16 + rb + r;
        int ncol = n0 + nb + nt * 16 + col;
        C[(size_t)mrow * ldc + ncol] = f2bf(accs[mt][nt][r]);
      }
}

// ---------------- stage C: per-mode 64ch complex contraction ----------------
__global__ __launch_bounds__(256) void modemix(
    const u16* __restrict__ P, const void* __restrict__ wre,
    const void* __restrict__ wim, u16* __restrict__ yt,
    const int* __restrict__ flag) {
  const int f32 = *flag;
  const int o = blockIdx.x >> 4;
  const int kxg = blockIdx.x & 15;
  const int tid = threadIdx.x;
  const int ky = tid & 63;
  const int kxj = tid >> 6;               // 0..3
  const int kx = kxg * 4 + kxj;
  float yR = 0.f, yI = 0.f;
  for (int i = 0; i < 64; ++i) {
    const u16* prow = P + i * 16384 + (2 * kx) * 128 + 2 * ky;
    unsigned p0 = *(const unsigned*)prow;          // [2kx][2ky], [2kx][2ky+1]
    unsigned p1 = *(const unsigned*)(prow + 128);  // [2kx+1][...]
    float p00 = bf2f((u16)(p0 & 0xFFFF)), p01 = bf2f((u16)(p0 >> 16));
    float p10 = bf2f((u16)(p1 & 0xFFFF)), p11 = bf2f((u16)(p1 >> 16));
    float xr = p00 - p11;
    float xi = p01 + p10;
    size_t widx = ((size_t)(i * 64 + o) * 64 + kx) * 64 + ky;
    float wr = rdx(wre, widx, f32);
    float wq = rdx(wim, widx, f32);
    yR += xr * wr - xi * wq;
    yI += xr * wq + xi * wr;
  }
  __shared__ u16 T[128][12];   // 24 B rows keep ushort4 (8 B) reads aligned
  T[2 * ky][2 * kxj]         = f2bf(yR);
  T[2 * ky][2 * kxj + 1]     = f2bf(yI);
  T[2 * ky + 1][2 * kxj]     = f2bf(yI);
  T[2 * ky + 1][2 * kxj + 1] = f2bf(-yR);
  __syncthreads();
  int r = tid >> 1, s = (tid & 1) * 4;
  u16* dst = yt + (size_t)o * 16384 + (size_t)r * 128 + kxg * 8 + s;
  ushort4 v;
  v.x = T[r][s]; v.y = T[r][s + 1]; v.z = T[r][s + 2]; v.w = T[r][s + 3];
  *(ushort4*)dst = v;
}

// ---------------- fused D+E: conv[o] stripe = (Gi @ yt[o]^T) @ Ct^T --------
// LDS stride 136 elems = 272 B = 17*16 (aligned b128).
__global__ __launch_bounds__(256) void inv_conv(
    const u16* __restrict__ Gi, const u16* __restrict__ Ct,
    const u16* __restrict__ yt, void* __restrict__ convV,
    const int* __restrict__ flag) {
  const int f32 = *flag;
  float* convF = (float*)convV;
  u16*   convH = (u16*)convV;
  const int m0 = blockIdx.x * 64;
  const int o  = blockIdx.y;
  __shared__ __align__(16) u16 lds[26112];   // 52 KB
  u16* As = lds;          // [64][136]  Gi tile;  later Cs (Ct tile)
  u16* Bs = lds + 8704;   // [128][136] yt;       later T [64][136]
  const int tid = threadIdx.x, lane = tid & 63, wave = tid >> 6;
  const int fr = lane & 15, koff = (lane >> 4) * 8;
  const int col = lane & 15, rb = (lane >> 4) * 4;
  {  // stage Gi tile (64x128)
    int r = tid >> 2, cs = (tid & 3) * 32;
    const u16* g = Gi + (size_t)(m0 + r) * 128 + cs;
    u16* d = As + r * 136 + cs;
#pragma unroll
    for (int j = 0; j < 4; ++j) *(uint4*)(d + 8 * j) = *(const uint4*)(g + 8 * j);
  }
  {  // stage full yt[o] (128x128)
    int r = tid >> 1, cs = (tid & 1) * 64;
    const u16* g = yt + (size_t)o * 16384 + (size_t)r * 128 + cs;
    u16* d = Bs + r * 136 + cs;
#pragma unroll
    for (int j = 0; j < 8; ++j) *(uint4*)(d + 8 * j) = *(const uint4*)(g + 8 * j);
  }
  __syncthreads();
  const int mb = (wave & 1) * 32, nh = (wave >> 1) * 64;
  f32x4 z = {0.f, 0.f, 0.f, 0.f};
  f32x4 acc1[2][4];
#pragma unroll
  for (int mt = 0; mt < 2; ++mt)
#pragma unroll
    for (int nt = 0; nt < 4; ++nt) acc1[mt][nt] = z;
  for (int k0 = 0; k0 < 128; k0 += 32) {
    bf16x8 a0 = *(const bf16x8*)(As + (mb + fr) * 136 + k0 + koff);
    bf16x8 a1 = *(const bf16x8*)(As + (mb + 16 + fr) * 136 + k0 + koff);
#pragma unroll
    for (int nt = 0; nt < 4; ++nt) {
      bf16x8 b = *(const bf16x8*)(Bs + (nh + nt * 16 + fr) * 136 + k0 + koff);
      acc1[0][nt] = __builtin_amdgcn_mfma_f32_16x16x32_bf16(a0, b, acc1[0][nt], 0, 0, 0);
      acc1[1][nt] = __builtin_amdgcn_mfma_f32_16x16x32_bf16(a1, b, acc1[1][nt], 0, 0, 0);
    }
  }
  __syncthreads();   // all As/Bs reads done before T overwrites Bs
  u16* T = Bs;       // [64][136], rows = m, cols = c
#pragma unroll
  for (int mt = 0; mt < 2; ++mt)
#pragma unroll
    for (int nt = 0; nt < 4; ++nt)
#pragma unroll
      for (int r = 0; r < 4; ++r)
        T[(mb + mt * 16 + rb + r) * 136 + nh + nt * 16 + col] = f2bf(acc1[mt][nt][r]);
  u16* Cs = lds;     // alias As
  const int mb2 = (wave & 1) * 32, nb2 = (wave >> 1) * 32;
  for (int nb0 = 0; nb0 < 8; ++nb0) {
    __syncthreads();
    {
      int r = tid >> 2, cs = (tid & 3) * 32;
      const u16* g = Ct + (size_t)(nb0 * 64 + r) * 128 + cs;
      u16* d = Cs + r * 136 + cs;
#pragma unroll
      for (int j = 0; j < 4; ++j) *(uint4*)(d + 8 * j) = *(const uint4*)(g + 8 * j);
    }
    __syncthreads();
    f32x4 acc2[2][2] = {{z, z}, {z, z}};
    for (int k0 = 0; k0 < 128; k0 += 32) {
      bf16x8 a0 = *(const bf16x8*)(T + (mb2 + fr) * 136 + k0 + koff);
      bf16x8 a1 = *(const bf16x8*)(T + (mb2 + 16 + fr) * 136 + k0 + koff);
      bf16x8 b0 = *(const bf16x8*)(Cs + (nb2 + fr) * 136 + k0 + koff);
      bf16x8 b1 = *(const bf16x8*)(Cs + (nb2 + 16 + fr) * 136 + k0 + koff);
      acc2[0][0] = __builtin_amdgcn_mfma_f32_16x16x32_bf16(a0, b0, acc2[0][0], 0, 0, 0);
      acc2[0][1] = __builtin_amdgcn_mfma_f32_16x16x32_bf16(a0, b1, acc2[0][1], 0, 0, 0);
      acc2[1][0] = __builtin_amdgcn_mfma_f32_16x16x32_bf16(a1, b0, acc2[1][0], 0, 0, 0);
      acc2[1][1] = __builtin_amdgcn_mfma_f32_16x16x32_bf16(a1, b1, acc2[1][1], 0, 0, 0);
    }
#pragma unroll
    for (int mt = 0; mt < 2; ++mt)
#pragma unroll
      for (int nt = 0; nt < 2; ++nt)
#pragma unroll
        for (int r = 0; r < 4; ++r) {
          size_t idx = (size_t)o * 262144 + (size_t)(m0 + mb2 + mt * 16 + rb + r) * 512
                     + nb0 * 64 + nb2 + nt * 16 + col;
          float v = acc2[mt][nt][r];
          if (f32) convF[idx] = v; else convH[idx] = f2bf(v);
        }
  }
}

// ---------------- stage F: MFMA skip GEMM + conv add + bias + gelu ---------
// out[o][p] = gelu(conv[o][p] + bias[o] + sum_i wbf[o][i]*x[i][p])
// Block: 128 px tile, all 64 o.  Grid 2048.  LDS 18.4 KB (x^T only);
// w-fragments load directly from global wbf (8 KB, L1-hot).
// launch_bounds(256,6): VGPR <= ~84 -> 6 waves/SIMD.
__global__ __launch_bounds__(256, 6) void skip_final_mfma(
    const void* __restrict__ x, const u16* __restrict__ wbf,
    const float* __restrict__ bias, void* __restrict__ outV,
    const int* __restrict__ flag) {
  const int f32 = *flag;
  float* outF = (float*)outV;
  u16*   outH = (u16*)outV;
  const size_t p0 = (size_t)blockIdx.x * 128;
  __shared__ __align__(16) u16 Bs[128][72];   // x^T: row px, col ch (swizzled)
  const int tid = threadIdx.x, lane = tid & 63, wave = tid >> 6;
  {  // stage x^T: 2 iters of (64 px x 64 ch); thread: 4 ch x 4 px reg-transpose
    const int cq = tid >> 4;          // 0..15 -> channels cq*4..+3
    const int pq = tid & 15;          // 0..15 -> px quad
    const int c0 = cq * 4;
    for (int ib = 0; ib < 2; ++ib) {
      const int px = ib * 64 + pq * 4;
      u16 v[4][4];   // [j ch][k px]
      if (f32) {
        const float* xp = (const float*)x + p0 + px;
#pragma unroll
        for (int j = 0; j < 4; ++j) {
          float4 t = *(const float4*)(xp + (size_t)(c0 + j) * 262144);
          v[j][0] = f2bf(t.x); v[j][1] = f2bf(t.y);
          v[j][2] = f2bf(t.z); v[j][3] = f2bf(t.w);
        }
      } else {
        const u16* xp = (const u16*)x + p0 + px;
#pragma unroll
        for (int j = 0; j < 4; ++j) {
          ushort4 t = *(const ushort4*)(xp + (size_t)(c0 + j) * 262144);
          v[j][0] = t.x; v[j][1] = t.y; v[j][2] = t.z; v[j][3] = t.w;
        }
      }
#pragma unroll
      for (int k = 0; k < 4; ++k) {
        int row = px + k;
        int cs = c0 ^ (((row >> 2) & 7) << 3);   // swizzled channel col
        ushort4 w4;
        w4.x = v[0][k]; w4.y = v[1][k]; w4.z = v[2][k]; w4.w = v[3][k];
        *(ushort4*)&Bs[row][cs] = w4;
      }
    }
  }
  __syncthreads();
  // wave -> 32-px slice; per wave M=64 (o) x N=32 (px) x K=64
  const int fr = lane & 15, koff = (lane >> 4) * 8;
  f32x4 z = {0.f, 0.f, 0.f, 0.f};
  f32x4 acc[4][2];   // [mi][ni]
#pragma unroll
  for (int mi = 0; mi < 4; ++mi)
#pragma unroll
    for (int ni = 0; ni < 2; ++ni) acc[mi][ni] = z;
#pragma unroll
  for (int k0 = 0; k0 < 64; k0 += 32) {
    bf16x8 a[4], b[2];
#pragma unroll
    for (int mi = 0; mi < 4; ++mi)
      a[mi] = *(const bf16x8*)&wbf[(size_t)(mi * 16 + fr) * 64 + k0 + koff];
#pragma unroll
    for (int ni = 0; ni < 2; ++ni) {
      int prow = wave * 32 + ni * 16 + fr;
      int sw = ((prow >> 2) & 7) << 3;
      b[ni] = *(const bf16x8*)&Bs[prow][(k0 + koff) ^ sw];
    }
#pragma unroll
    for (int mi = 0; mi < 4; ++mi)
#pragma unroll
      for (int ni = 0; ni < 2; ++ni)
        acc[mi][ni] = __builtin_amdgcn_mfma_f32_16x16x32_bf16(a[mi], b[ni], acc[mi][ni], 0, 0, 0);
  }
  // epilogue: conv add + bias + gelu, in place on d_out
  const int col = lane & 15, rb = (lane >> 4) * 4;
#pragma unroll
  for (int mi = 0; mi < 4; ++mi)
#pragma unroll
    for (int ni = 0; ni < 2; ++ni)
#pragma unroll
      for (int r = 0; r < 4; ++r) {
        int o = mi * 16 + rb + r;
        size_t idx = (size_t)o * 262144 + p0 + wave * 32 + ni * 16 + col;
        float cv = f32 ? outF[idx] : bf2f(outH[idx]);
        float v = acc[mi][ni][r] + cv + bias[o];
        // gelu(tanh approx) = v * sigmoid(2*0.7978845608*(v + 0.044715 v^3))
        float zz = 1.5957691216f * (v + 0.044715f * v * v * v);
        float g = v / (1.f + __expf(-zz));
        if (f32) outF[idx] = g; else outH[idx] = f2bf(g);
      }
}

extern "C" void kernel_launch(void* const* d_in, const int* in_sizes, int n_in,
                              void* d_out, int out_size, void* d_ws, size_t ws_size,
                              hipStream_t stream) {
  const void* x     = d_in[0];   // (64,512,512)
  const void* wre   = d_in[1];   // (64,64,64,64)
  const void* wim   = d_in[2];
  const void* bconv = d_in[3];   // (64,)
  const void* wskip = d_in[4];   // (64,64)
  const void* bskip = d_in[5];   // (64,)
  char* ws = (char*)d_ws;

  // ws layout (total 2.5 MB)
  u16*   EW   = (u16*)(ws);                            // 128 KB
  u16*   Gi   = (u16*)(ws + (1 << 17));                // 128 KB
  u16*   Ct   = (u16*)(ws + (2 << 17));                // 128 KB
  u16*   wbf  = (u16*)(ws + 3 * (1 << 17));            // 8 KB
  float* bias = (float*)(ws + 3 * (1 << 17) + 16384);  // 256 B
  int*   flag = (int*)(ws + 3 * (1 << 17) + 16640);    // 4 B
  u16*   yt   = (u16*)(ws + (1 << 19));                // 2 MB
  // d_out doubles as scratch before stage D+E (byte offsets; fits either dtype):
  u16* t1T = (u16*)d_out;                    // [0, 8MB):  64 x (128x512) bf16
  u16* P   = (u16*)((char*)d_out + (8 << 20));  // [8,10MB): 64 x (128x128) bf16

  sniff<<<1, 64, 0, stream>>>((const unsigned*)x, flag);
  init_tables<<<256, 256, 0, stream>>>(wskip, bconv, bskip, flag, EW, Gi, Ct, wbf, bias);
  // A: t1T[i](128x512) = EW @ x[i]^T        M=128 N=512 K=512, batch 64
  gemm_bt_x<<<dim3(8, 1, 64), 512, 0, stream>>>(EW, 512, x, 512, 262144, t1T, 512, 65536, 512, flag);
  // B: P[i](128x128) = EW @ t1T[i]^T        M=128 N=128 K=512
  gemm_bt<<<dim3(2, 2, 64), 256, 0, stream>>>(EW, 512, 0, t1T, 512, 65536, P, 128, 16384, 512);
  // C: mode mix -> yt[o] in ws (sym 2x2 layout)
  modemix<<<1024, 256, 0, stream>>>(P, wre, wim, yt, flag);
  // D+E fused: conv -> d_out (overwrites t1T/P scratch, both dead)
  inv_conv<<<dim3(8, 64), 256, 0, stream>>>(Gi, Ct, yt, d_out, flag);
  // F: MFMA skip + conv + bias + gelu (in-place on d_out)
  skip_final_mfma<<<2048, 256, 0, stream>>>(x, wbf, bias, d_out, flag);
}

// Round 5
// 295.542 us; speedup vs baseline: 1.0730x; 1.0136x over previous
//
#include <hip/hip_runtime.h>

// FourierLayer: rfft2 -> keep 64x64 modes -> per-mode channel mix -> irfft2
// + channelwise skip + gelu.  All DFTs collapse to dense GEMMs (only 64x64
// modes survive).  External dtype (fp32 vs bf16) is UNKNOWN -> detected at
// runtime by `sniff`.  Internal intermediates are always bf16.
//
// Memory plan:
//   ws:    EW/Gi/Ct/wbf/bias/flag tables (0.41 MB) + yt (2 MB)
//   d_out: phase1 t1T [0,8MB) -> phase2 P [8,10MB) -> conv (full, out dtype)
// Stages:
//   A: t1T[i](128x512) = EW(128x512) @ x[i](512x512)^T      (W-axis DFT)
//      (R3: 512-thread blocks, full M=128 per n-tile -> x fetched ONCE)
//   B: P[i](128x128)   = EW(128x512) @ t1T[i]^T             (H-axis DFT)
//   C: yt[o](128x128)  = mode mix, sym 2x2 blocks [[yR,yI],[yI,-yR]] -> ws
//      (R4: i-loop unrolled x8 w/ explicit load batches -> 32 loads in
//       flight; dtype branch hoisted.  VGPR=16 + 4 dependent loads/iter was
//       latency-bound at 1.25 TB/s.)
//   D+E fused: conv[o] = (Gi @ yt[o]^T) @ Ct^T -> d_out
//   F: out = gelu(conv + bias + w_skip@x)  -- MFMA skip GEMM, in-place d_out
//      (R4: epilogue loads ALL 32 conv values first (stores can't be hoisted
//       past by compiler -> was serializing), launch_bounds(256,4).)

using bf16x8 = __attribute__((ext_vector_type(8))) short;
using f32x4  = __attribute__((ext_vector_type(4))) float;
typedef unsigned short u16;

__device__ __forceinline__ u16 f2bf(float f) {
  unsigned u = __float_as_uint(f);
  u = u + 0x7FFFu + ((u >> 16) & 1u);   // round-to-nearest-even
  return (u16)(u >> 16);
}
__device__ __forceinline__ float bf2f(u16 v) {
  return __uint_as_float(((unsigned)v) << 16);
}
// flag==1 -> externals are fp32; flag==0 -> externals are bf16
__device__ __forceinline__ float rdx(const void* p, size_t i, int f32) {
  return f32 ? ((const float*)p)[i] : bf2f(((const u16*)p)[i]);
}

// ---------------- dtype sniff ----------------------------------------------
__global__ void sniff(const unsigned* __restrict__ xw, int* __restrict__ flag) {
  unsigned u = xw[threadIdx.x];
  int e = (u >> 7) & 0xFF;                  // bf16-pair: exponent of low bf16
  unsigned long long m = __ballot(e >= 110 && e <= 130);
  if (threadIdx.x == 0) *flag = (__popcll(m) < 32) ? 1 : 0;   // 1 = fp32
}

// ---------------- twiddle tables + wskip bf16 + fused bias ------------------
__global__ __launch_bounds__(256) void init_tables(
    const void* __restrict__ wskip, const void* __restrict__ bconv,
    const void* __restrict__ bskip, const int* __restrict__ flag,
    u16* __restrict__ EW,    // [128][512]  fwd DFT (stages A and B)
    u16* __restrict__ Gi,    // [512][128]  inv DFT rows=h, cols=2kx|2kx+1
    u16* __restrict__ Ct,    // [512][128]  irfft rows=w
    u16* __restrict__ wbf,   // [o][i] skip weights, bf16 (MFMA A operand)
    float* __restrict__ bias) {
  const int f32 = *flag;
  int t = blockIdx.x * blockDim.x + threadIdx.x;   // 0..65535
  {
    // EW[m][n]: f=m>>1, part=m&1 -> part? -sin : cos of 2*pi*f*n/512
    int m = t >> 9, n = t & 511;
    int f = m >> 1, part = m & 1;
    int idx = (f * n) & 511;
    float ang = 0.01227184630308513f * (float)idx;  // 2*pi/512
    float s, c; __sincosf(ang, &s, &c);
    EW[t] = f2bf(part ? -s : c);
  }
  {
    int h = t >> 7, cc = t & 127;
    int f = cc >> 1, part = cc & 1;
    int idx = (f * h) & 511;
    float ang = 0.01227184630308513f * (float)idx;
    float s, c; __sincosf(ang, &s, &c);
    // inverse along H: e^{+i}/512 -> (cos, -sin) against [[yR,yI],[yI,-yR]]
    Gi[t] = f2bf((part ? -s : c) * (1.0f / 512.0f));
    // irfft along W: (1 if ky==0 else 2)/512 * (cos | -sin)
    float scale = (f == 0 ? 1.0f : 2.0f) * (1.0f / 512.0f);
    Ct[t] = f2bf((part ? -s : c) * scale);
  }
  if (t < 4096) wbf[t] = f2bf(rdx(wskip, t, f32));   // [o][i] row-major
  if (t < 64) bias[t] = rdx(bconv, t, f32) + rdx(bskip, t, f32);
}

// ---------------- stage A GEMM: B operand is the external x ----------------
// C[m][n] = sum_k A[m][k] * Bt[n][k];  blockIdx.z = batch (channel i).
// 512 threads, full M=128 x N=64 per block: every x tile fetched once.
// LDS row stride 72 elems = 144 B = 9*16 B (every b128 16B-aligned).
__global__ __launch_bounds__(512) void gemm_bt_x(
    const u16* __restrict__ A,  int lda,
    const void* __restrict__ BtV, int ldb, long long sB,
    u16* __restrict__ C,        int ldc, long long sC,
    int K, const int* __restrict__ flag) {
  const int f32 = *flag;
  const float* BtF = (const float*)BtV + (long long)blockIdx.z * sB;
  const u16*   BtH = (const u16*)BtV + (long long)blockIdx.z * sB;
  C += (long long)blockIdx.z * sC;
  const int n0 = blockIdx.x * 64;
  __shared__ __align__(16) u16 As[128][72];   // 18.4 KB
  __shared__ __align__(16) u16 Bs[64][72];    //  9.2 KB
  const int tid  = threadIdx.x;
  const int lane = tid & 63, wave = tid >> 6;        // 8 waves
  const int srowA = tid >> 2, ssegA = (tid & 3) * 8; // 128 rows x 32 cols
  const int srowB = tid >> 3, ssegB = (tid & 7) * 4; //  64 rows x 32 cols
  const int mb = (wave & 3) * 32, nb = (wave >> 2) * 32;
  const int fr = lane & 15, koff = (lane >> 4) * 8;
  f32x4 z = {0.f, 0.f, 0.f, 0.f};
  f32x4 acc00 = z, acc01 = z, acc10 = z, acc11 = z;
  for (int k0 = 0; k0 < K; k0 += 32) {
    __syncthreads();
    *(uint4*)&As[srowA][ssegA] = *(const uint4*)&A[(size_t)srowA * lda + k0 + ssegA];
    size_t bofs = (size_t)(n0 + srowB) * ldb + k0 + ssegB;
    if (f32) {
      float4 u = *(const float4*)(BtF + bofs);
      ushort4 w;
      w.x = f2bf(u.x); w.y = f2bf(u.y); w.z = f2bf(u.z); w.w = f2bf(u.w);
      *(ushort4*)&Bs[srowB][ssegB] = w;
    } else {
      *(ushort4*)&Bs[srowB][ssegB] = *(const ushort4*)(BtH + bofs);
    }
    __syncthreads();
    bf16x8 a0 = *(const bf16x8*)&As[mb + fr][koff];
    bf16x8 a1 = *(const bf16x8*)&As[mb + 16 + fr][koff];
    bf16x8 b0 = *(const bf16x8*)&Bs[nb + fr][koff];
    bf16x8 b1 = *(const bf16x8*)&Bs[nb + 16 + fr][koff];
    acc00 = __builtin_amdgcn_mfma_f32_16x16x32_bf16(a0, b0, acc00, 0, 0, 0);
    acc01 = __builtin_amdgcn_mfma_f32_16x16x32_bf16(a0, b1, acc01, 0, 0, 0);
    acc10 = __builtin_amdgcn_mfma_f32_16x16x32_bf16(a1, b0, acc10, 0, 0, 0);
    acc11 = __builtin_amdgcn_mfma_f32_16x16x32_bf16(a1, b1, acc11, 0, 0, 0);
  }
  // C/D layout: col = lane&15, row = (lane>>4)*4 + reg
  const int col = lane & 15, rb = (lane >> 4) * 4;
  f32x4 accs[2][2] = {{acc00, acc01}, {acc10, acc11}};
  for (int mt = 0; mt < 2; ++mt)
    for (int nt = 0; nt < 2; ++nt)
      for (int r = 0; r < 4; ++r) {
        int mrow = mb + mt * 16 + rb + r;
        int ncol = n0 + nb + nt * 16 + col;
        C[(size_t)mrow * ldc + ncol] = f2bf(accs[mt][nt][r]);
      }
}

// ---------------- stage B GEMM: all-bf16 internal --------------------------
__global__ __launch_bounds__(256) void gemm_bt(
    const u16* __restrict__ A,  int lda, long long sA,
    const u16* __restrict__ Bt, int ldb, long long sB,
    u16* __restrict__ C,        int ldc, long long sC,
    int K) {
  A  += (long long)blockIdx.z * sA;
  Bt += (long long)blockIdx.z * sB;
  C  += (long long)blockIdx.z * sC;
  const int m0 = blockIdx.y * 64, n0 = blockIdx.x * 64;
  __shared__ __align__(16) u16 As[64][72];
  __shared__ __align__(16) u16 Bs[64][72];
  const int tid  = threadIdx.x;
  const int lane = tid & 63, wave = tid >> 6;
  const int srow = tid >> 2, sseg = (tid & 3) * 8;
  const int mb = (wave & 1) * 32, nb = (wave >> 1) * 32;
  const int fr = lane & 15, koff = (lane >> 4) * 8;
  f32x4 z = {0.f, 0.f, 0.f, 0.f};
  f32x4 acc00 = z, acc01 = z, acc10 = z, acc11 = z;
  for (int k0 = 0; k0 < K; k0 += 32) {
    __syncthreads();
    *(uint4*)&As[srow][sseg] = *(const uint4*)&A[(size_t)(m0 + srow) * lda + k0 + sseg];
    *(uint4*)&Bs[srow][sseg] = *(const uint4*)&Bt[(size_t)(n0 + srow) * ldb + k0 + sseg];
    __syncthreads();
    bf16x8 a0 = *(const bf16x8*)&As[mb + fr][koff];
    bf16x8 a1 = *(const bf16x8*)&As[mb + 16 + fr][koff];
    bf16x8 b0 = *(const bf16x8*)&Bs[nb + fr][koff];
    bf16x8 b1 = *(const bf16x8*)&Bs[nb + 16 + fr][koff];
    acc00 = __builtin_amdgcn_mfma_f32_16x16x32_bf16(a0, b0, acc00, 0, 0, 0);
    acc01 = __builtin_amdgcn_mfma_f32_16x16x32_bf16(a0, b1, acc01, 0, 0, 0);
    acc10 = __builtin_amdgcn_mfma_f32_16x16x32_bf16(a1, b0, acc10, 0, 0, 0);
    acc11 = __builtin_amdgcn_mfma_f32_16x16x32_bf16(a1, b1, acc11, 0, 0, 0);
  }
  const int col = lane & 15, rb = (lane >> 4) * 4;
  f32x4 accs[2][2] = {{acc00, acc01}, {acc10, acc11}};
  for (int mt = 0; mt < 2; ++mt)
    for (int nt = 0; nt < 2; ++nt)
      for (int r = 0; r < 4; ++r) {
        int mrow = m0 + mb + mt * 16 + rb + r;
        int ncol = n0 + nb + nt * 16 + col;
        C[(size_t)mrow * ldc + ncol] = f2bf(accs[mt][nt][r]);
      }
}

// ---------------- stage C: per-mode 64ch complex contraction ----------------
// R4: i-loop unrolled x8, loads batched ahead of compute (32 in flight),
// uniform dtype branch hoisted out of the loop.
__global__ __launch_bounds__(256) void modemix(
    const u16* __restrict__ P, const void* __restrict__ wre,
    const void* __restrict__ wim, u16* __restrict__ yt,
    const int* __restrict__ flag) {
  const int f32 = *flag;
  const int o = blockIdx.x >> 4;
  const int kxg = blockIdx.x & 15;
  const int tid = threadIdx.x;
  const int ky = tid & 63;
  const int kxj = tid >> 6;               // 0..3
  const int kx = kxg * 4 + kxj;
  const u16* Pb = P + (2 * kx) * 128 + 2 * ky;
  const size_t wb = (size_t)o * 4096 + (size_t)kx * 64 + ky;
  float yR = 0.f, yI = 0.f;
  if (f32) {
    const float* wrp = (const float*)wre + wb;
    const float* wqp = (const float*)wim + wb;
    for (int i = 0; i < 64; i += 8) {
      unsigned p0[8], p1[8]; float wr[8], wq[8];
#pragma unroll
      for (int u = 0; u < 8; ++u) {
        const u16* prow = Pb + (size_t)(i + u) * 16384;
        p0[u] = *(const unsigned*)prow;          // [2kx][2ky], [2kx][2ky+1]
        p1[u] = *(const unsigned*)(prow + 128);  // [2kx+1][...]
        wr[u] = wrp[(size_t)(i + u) * 262144];
        wq[u] = wqp[(size_t)(i + u) * 262144];
      }
#pragma unroll
      for (int u = 0; u < 8; ++u) {
        float p00 = bf2f((u16)(p0[u] & 0xFFFF)), p01 = bf2f((u16)(p0[u] >> 16));
        float p10 = bf2f((u16)(p1[u] & 0xFFFF)), p11 = bf2f((u16)(p1[u] >> 16));
        float xr = p00 - p11, xi = p01 + p10;
        yR += xr * wr[u] - xi * wq[u];
        yI += xr * wq[u] + xi * wr[u];
      }
    }
  } else {
    const u16* wrp = (const u16*)wre + wb;
    const u16* wqp = (const u16*)wim + wb;
    for (int i = 0; i < 64; i += 8) {
      unsigned p0[8], p1[8]; u16 wr[8], wq[8];
#pragma unroll
      for (int u = 0; u < 8; ++u) {
        const u16* prow = Pb + (size_t)(i + u) * 16384;
        p0[u] = *(const unsigned*)prow;
        p1[u] = *(const unsigned*)(prow + 128);
        wr[u] = wrp[(size_t)(i + u) * 262144];
        wq[u] = wqp[(size_t)(i + u) * 262144];
      }
#pragma unroll
      for (int u = 0; u < 8; ++u) {
        float p00 = bf2f((u16)(p0[u] & 0xFFFF)), p01 = bf2f((u16)(p0[u] >> 16));
        float p10 = bf2f((u16)(p1[u] & 0xFFFF)), p11 = bf2f((u16)(p1[u] >> 16));
        float xr = p00 - p11, xi = p01 + p10;
        float wrf = bf2f(wr[u]), wqf = bf2f(wq[u]);
        yR += xr * wrf - xi * wqf;
        yI += xr * wqf + xi * wrf;
      }
    }
  }
  __shared__ u16 T[128][12];   // 24 B rows keep ushort4 (8 B) reads aligned
  T[2 * ky][2 * kxj]         = f2bf(yR);
  T[2 * ky][2 * kxj + 1]     = f2bf(yI);
  T[2 * ky + 1][2 * kxj]     = f2bf(yI);
  T[2 * ky + 1][2 * kxj + 1] = f2bf(-yR);
  __syncthreads();
  int r = tid >> 1, s = (tid & 1) * 4;
  u16* dst = yt + (size_t)o * 16384 + (size_t)r * 128 + kxg * 8 + s;
  ushort4 v;
  v.x = T[r][s]; v.y = T[r][s + 1]; v.z = T[r][s + 2]; v.w = T[r][s + 3];
  *(ushort4*)dst = v;
}

// ---------------- fused D+E: conv[o] stripe = (Gi @ yt[o]^T) @ Ct^T --------
// LDS stride 136 elems = 272 B = 17*16 (aligned b128).
__global__ __launch_bounds__(256) void inv_conv(
    const u16* __restrict__ Gi, const u16* __restrict__ Ct,
    const u16* __restrict__ yt, void* __restrict__ convV,
    const int* __restrict__ flag) {
  const int f32 = *flag;
  float* convF = (float*)convV;
  u16*   convH = (u16*)convV;
  const int m0 = blockIdx.x * 64;
  const int o  = blockIdx.y;
  __shared__ __align__(16) u16 lds[26112];   // 52 KB
  u16* As = lds;          // [64][136]  Gi tile;  later Cs (Ct tile)
  u16* Bs = lds + 8704;   // [128][136] yt;       later T [64][136]
  const int tid = threadIdx.x, lane = tid & 63, wave = tid >> 6;
  const int fr = lane & 15, koff = (lane >> 4) * 8;
  const int col = lane & 15, rb = (lane >> 4) * 4;
  {  // stage Gi tile (64x128)
    int r = tid >> 2, cs = (tid & 3) * 32;
    const u16* g = Gi + (size_t)(m0 + r) * 128 + cs;
    u16* d = As + r * 136 + cs;
#pragma unroll
    for (int j = 0; j < 4; ++j) *(uint4*)(d + 8 * j) = *(const uint4*)(g + 8 * j);
  }
  {  // stage full yt[o] (128x128)
    int r = tid >> 1, cs = (tid & 1) * 64;
    const u16* g = yt + (size_t)o * 16384 + (size_t)r * 128 + cs;
    u16* d = Bs + r * 136 + cs;
#pragma unroll
    for (int j = 0; j < 8; ++j) *(uint4*)(d + 8 * j) = *(const uint4*)(g + 8 * j);
  }
  __syncthreads();
  const int mb = (wave & 1) * 32, nh = (wave >> 1) * 64;
  f32x4 z = {0.f, 0.f, 0.f, 0.f};
  f32x4 acc1[2][4];
#pragma unroll
  for (int mt = 0; mt < 2; ++mt)
#pragma unroll
    for (int nt = 0; nt < 4; ++nt) acc1[mt][nt] = z;
  for (int k0 = 0; k0 < 128; k0 += 32) {
    bf16x8 a0 = *(const bf16x8*)(As + (mb + fr) * 136 + k0 + koff);
    bf16x8 a1 = *(const bf16x8*)(As + (mb + 16 + fr) * 136 + k0 + koff);
#pragma unroll
    for (int nt = 0; nt < 4; ++nt) {
      bf16x8 b = *(const bf16x8*)(Bs + (nh + nt * 16 + fr) * 136 + k0 + koff);
      acc1[0][nt] = __builtin_amdgcn_mfma_f32_16x16x32_bf16(a0, b, acc1[0][nt], 0, 0, 0);
      acc1[1][nt] = __builtin_amdgcn_mfma_f32_16x16x32_bf16(a1, b, acc1[1][nt], 0, 0, 0);
    }
  }
  __syncthreads();   // all As/Bs reads done before T overwrites Bs
  u16* T = Bs;       // [64][136], rows = m, cols = c
#pragma unroll
  for (int mt = 0; mt < 2; ++mt)
#pragma unroll
    for (int nt = 0; nt < 4; ++nt)
#pragma unroll
      for (int r = 0; r < 4; ++r)
        T[(mb + mt * 16 + rb + r) * 136 + nh + nt * 16 + col] = f2bf(acc1[mt][nt][r]);
  u16* Cs = lds;     // alias As
  const int mb2 = (wave & 1) * 32, nb2 = (wave >> 1) * 32;
  for (int nb0 = 0; nb0 < 8; ++nb0) {
    __syncthreads();
    {
      int r = tid >> 2, cs = (tid & 3) * 32;
      const u16* g = Ct + (size_t)(nb0 * 64 + r) * 128 + cs;
      u16* d = Cs + r * 136 + cs;
#pragma unroll
      for (int j = 0; j < 4; ++j) *(uint4*)(d + 8 * j) = *(const uint4*)(g + 8 * j);
    }
    __syncthreads();
    f32x4 acc2[2][2] = {{z, z}, {z, z}};
    for (int k0 = 0; k0 < 128; k0 += 32) {
      bf16x8 a0 = *(const bf16x8*)(T + (mb2 + fr) * 136 + k0 + koff);
      bf16x8 a1 = *(const bf16x8*)(T + (mb2 + 16 + fr) * 136 + k0 + koff);
      bf16x8 b0 = *(const bf16x8*)(Cs + (nb2 + fr) * 136 + k0 + koff);
      bf16x8 b1 = *(const bf16x8*)(Cs + (nb2 + 16 + fr) * 136 + k0 + koff);
      acc2[0][0] = __builtin_amdgcn_mfma_f32_16x16x32_bf16(a0, b0, acc2[0][0], 0, 0, 0);
      acc2[0][1] = __builtin_amdgcn_mfma_f32_16x16x32_bf16(a0, b1, acc2[0][1], 0, 0, 0);
      acc2[1][0] = __builtin_amdgcn_mfma_f32_16x16x32_bf16(a1, b0, acc2[1][0], 0, 0, 0);
      acc2[1][1] = __builtin_amdgcn_mfma_f32_16x16x32_bf16(a1, b1, acc2[1][1], 0, 0, 0);
    }
#pragma unroll
    for (int mt = 0; mt < 2; ++mt)
#pragma unroll
      for (int nt = 0; nt < 2; ++nt)
#pragma unroll
        for (int r = 0; r < 4; ++r) {
          size_t idx = (size_t)o * 262144 + (size_t)(m0 + mb2 + mt * 16 + rb + r) * 512
                     + nb0 * 64 + nb2 + nt * 16 + col;
          float v = acc2[mt][nt][r];
          if (f32) convF[idx] = v; else convH[idx] = f2bf(v);
        }
  }
}

// ---------------- stage F: MFMA skip GEMM + conv add + bias + gelu ---------
// out[o][p] = gelu(conv[o][p] + bias[o] + sum_i wbf[o][i]*x[i][p])
// Block: 128 px tile, all 64 o.  Grid 2048.  LDS 18.4 KB (x^T only);
// w-fragments load directly from global wbf (8 KB, L1-hot).
// R4: epilogue = batch-load all 32 conv values -> compute -> store
// (loads can't be hoisted past stores by the compiler; was serializing).
__global__ __launch_bounds__(256, 4) void skip_final_mfma(
    const void* __restrict__ x, const u16* __restrict__ wbf,
    const float* __restrict__ bias, void* __restrict__ outV,
    const int* __restrict__ flag) {
  const int f32 = *flag;
  float* outF = (float*)outV;
  u16*   outH = (u16*)outV;
  const size_t p0 = (size_t)blockIdx.x * 128;
  __shared__ __align__(16) u16 Bs[128][72];   // x^T: row px, col ch (swizzled)
  const int tid = threadIdx.x, lane = tid & 63, wave = tid >> 6;
  {  // stage x^T: 2 iters of (64 px x 64 ch); thread: 4 ch x 4 px reg-transpose
    const int cq = tid >> 4;          // 0..15 -> channels cq*4..+3
    const int pq = tid & 15;          // 0..15 -> px quad
    const int c0 = cq * 4;
    for (int ib = 0; ib < 2; ++ib) {
      const int px = ib * 64 + pq * 4;
      u16 v[4][4];   // [j ch][k px]
      if (f32) {
        const float* xp = (const float*)x + p0 + px;
#pragma unroll
        for (int j = 0; j < 4; ++j) {
          float4 t = *(const float4*)(xp + (size_t)(c0 + j) * 262144);
          v[j][0] = f2bf(t.x); v[j][1] = f2bf(t.y);
          v[j][2] = f2bf(t.z); v[j][3] = f2bf(t.w);
        }
      } else {
        const u16* xp = (const u16*)x + p0 + px;
#pragma unroll
        for (int j = 0; j < 4; ++j) {
          ushort4 t = *(const ushort4*)(xp + (size_t)(c0 + j) * 262144);
          v[j][0] = t.x; v[j][1] = t.y; v[j][2] = t.z; v[j][3] = t.w;
        }
      }
#pragma unroll
      for (int k = 0; k < 4; ++k) {
        int row = px + k;
        int cs = c0 ^ (((row >> 2) & 7) << 3);   // swizzled channel col
        ushort4 w4;
        w4.x = v[0][k]; w4.y = v[1][k]; w4.z = v[2][k]; w4.w = v[3][k];
        *(ushort4*)&Bs[row][cs] = w4;
      }
    }
  }
  __syncthreads();
  // wave -> 32-px slice; per wave M=64 (o) x N=32 (px) x K=64
  const int fr = lane & 15, koff = (lane >> 4) * 8;
  f32x4 z = {0.f, 0.f, 0.f, 0.f};
  f32x4 acc[4][2];   // [mi][ni]
#pragma unroll
  for (int mi = 0; mi < 4; ++mi)
#pragma unroll
    for (int ni = 0; ni < 2; ++ni) acc[mi][ni] = z;
#pragma unroll
  for (int k0 = 0; k0 < 64; k0 += 32) {
    bf16x8 a[4], b[2];
#pragma unroll
    for (int mi = 0; mi < 4; ++mi)
      a[mi] = *(const bf16x8*)&wbf[(size_t)(mi * 16 + fr) * 64 + k0 + koff];
#pragma unroll
    for (int ni = 0; ni < 2; ++ni) {
      int prow = wave * 32 + ni * 16 + fr;
      int sw = ((prow >> 2) & 7) << 3;
      b[ni] = *(const bf16x8*)&Bs[prow][(k0 + koff) ^ sw];
    }
#pragma unroll
    for (int mi = 0; mi < 4; ++mi)
#pragma unroll
      for (int ni = 0; ni < 2; ++ni)
        acc[mi][ni] = __builtin_amdgcn_mfma_f32_16x16x32_bf16(a[mi], b[ni], acc[mi][ni], 0, 0, 0);
  }
  // epilogue: batch-load conv, then compute + store (in place on d_out)
  const int col = lane & 15, rb = (lane >> 4) * 4;
  const size_t pb = p0 + wave * 32 + col;
  float cv[4][2][4];
  if (f32) {
#pragma unroll
    for (int mi = 0; mi < 4; ++mi)
#pragma unroll
      for (int ni = 0; ni < 2; ++ni)
#pragma unroll
        for (int r = 0; r < 4; ++r)
          cv[mi][ni][r] = outF[(size_t)(mi * 16 + rb + r) * 262144 + pb + ni * 16];
  } else {
#pragma unroll
    for (int mi = 0; mi < 4; ++mi)
#pragma unroll
      for (int ni = 0; ni < 2; ++ni)
#pragma unroll
        for (int r = 0; r < 4; ++r)
          cv[mi][ni][r] = bf2f(outH[(size_t)(mi * 16 + rb + r) * 262144 + pb + ni * 16]);
  }
#pragma unroll
  for (int mi = 0; mi < 4; ++mi)
#pragma unroll
    for (int ni = 0; ni < 2; ++ni)
#pragma unroll
      for (int r = 0; r < 4; ++r) {
        int o = mi * 16 + rb + r;
        float v = acc[mi][ni][r] + cv[mi][ni][r] + bias[o];
        // gelu(tanh approx) = v * sigmoid(2*0.7978845608*(v + 0.044715 v^3))
        float zz = 1.5957691216f * (v + 0.044715f * v * v * v);
        float g = v / (1.f + __expf(-zz));
        size_t idx = (size_t)o * 262144 + pb + ni * 16;
        if (f32) outF[idx] = g; else outH[idx] = f2bf(g);
      }
}

extern "C" void kernel_launch(void* const* d_in, const int* in_sizes, int n_in,
                              void* d_out, int out_size, void* d_ws, size_t ws_size,
                              hipStream_t stream) {
  const void* x     = d_in[0];   // (64,512,512)
  const void* wre   = d_in[1];   // (64,64,64,64)
  const void* wim   = d_in[2];
  const void* bconv = d_in[3];   // (64,)
  const void* wskip = d_in[4];   // (64,64)
  const void* bskip = d_in[5];   // (64,)
  char* ws = (char*)d_ws;

  // ws layout (total 2.5 MB)
  u16*   EW   = (u16*)(ws);                            // 128 KB
  u16*   Gi   = (u16*)(ws + (1 << 17));                // 128 KB
  u16*   Ct   = (u16*)(ws + (2 << 17));                // 128 KB
  u16*   wbf  = (u16*)(ws + 3 * (1 << 17));            // 8 KB
  float* bias = (float*)(ws + 3 * (1 << 17) + 16384);  // 256 B
  int*   flag = (int*)(ws + 3 * (1 << 17) + 16640);    // 4 B
  u16*   yt   = (u16*)(ws + (1 << 19));                // 2 MB
  // d_out doubles as scratch before stage D+E (byte offsets; fits either dtype):
  u16* t1T = (u16*)d_out;                    // [0, 8MB):  64 x (128x512) bf16
  u16* P   = (u16*)((char*)d_out + (8 << 20));  // [8,10MB): 64 x (128x128) bf16

  sniff<<<1, 64, 0, stream>>>((const unsigned*)x, flag);
  init_tables<<<256, 256, 0, stream>>>(wskip, bconv, bskip, flag, EW, Gi, Ct, wbf, bias);
  // A: t1T[i](128x512) = EW @ x[i]^T        M=128 N=512 K=512, batch 64
  gemm_bt_x<<<dim3(8, 1, 64), 512, 0, stream>>>(EW, 512, x, 512, 262144, t1T, 512, 65536, 512, flag);
  // B: P[i](128x128) = EW @ t1T[i]^T        M=128 N=128 K=512
  gemm_bt<<<dim3(2, 2, 64), 256, 0, stream>>>(EW, 512, 0, t1T, 512, 65536, P, 128, 16384, 512);
  // C: mode mix -> yt[o] in ws (sym 2x2 layout)
  modemix<<<1024, 256, 0, stream>>>(P, wre, wim, yt, flag);
  // D+E fused: conv -> d_out (overwrites t1T/P scratch, both dead)
  inv_conv<<<dim3(8, 64), 256, 0, stream>>>(Gi, Ct, yt, d_out, flag);
  // F: MFMA skip + conv + bias + gelu (in-place on d_out)
  skip_final_mfma<<<2048, 256, 0, stream>>>(x, wbf, bias, d_out, flag);
}